// Round 3
// baseline (1070.758 us; speedup 1.0000x reference)
//
#include <hip/hip_runtime.h>
#include <math.h>

#define B_   4
#define NQ_  1024
#define NK_  1024
#define D_   1024
#define H_   16
#define DH_  64
#define DFF_ 4096
#define SCALE_ (1.0f/32.0f)   // 1/sqrt(D)
#define LN_EPS_ 1e-5f

// ---------------------------------------------------------------------------
// Split-bf16 arithmetic: x = hi + lo, each bf16 (RNE). 3-term MFMA product
// Ah*Bh + Ah*Bl + Al*Bh has ~2^-16 relative error — fp32-grade for this net.
// ---------------------------------------------------------------------------
typedef __attribute__((ext_vector_type(8))) short bf16x8_t;  // 8 bf16 = 4 VGPR
typedef __attribute__((ext_vector_type(4))) float f32x4_t;

__device__ __forceinline__ ushort f2bf_rne(float x) {
    unsigned u = __float_as_uint(x);
    unsigned r = (u + 0x7FFFu + ((u >> 16) & 1u)) >> 16;
    return (ushort)r;
}
__device__ __forceinline__ float bf2f(ushort h) {
    return __uint_as_float(((unsigned)h) << 16);
}

// ---------------------------------------------------------------------------
// Elementwise fp32 -> (hi,lo) bf16 planes. n4 = n/4.
// ---------------------------------------------------------------------------
__global__ __launch_bounds__(256) void split_rows(const float* __restrict__ src,
        ushort* __restrict__ hi, ushort* __restrict__ lo, int n4)
{
    int i = blockIdx.x * 256 + threadIdx.x;
    if (i >= n4) return;
    float4 v = ((const float4*)src)[i];
    ushort4 h, l;
    h.x = f2bf_rne(v.x); l.x = f2bf_rne(v.x - bf2f(h.x));
    h.y = f2bf_rne(v.y); l.y = f2bf_rne(v.y - bf2f(h.y));
    h.z = f2bf_rne(v.z); l.z = f2bf_rne(v.z - bf2f(h.z));
    h.w = f2bf_rne(v.w); l.w = f2bf_rne(v.w - bf2f(h.w));
    ((ushort4*)hi)[i] = h;
    ((ushort4*)lo)[i] = l;
}

// ---------------------------------------------------------------------------
// Weight split + transpose: in W[K][N] fp32 -> out planes Wt[N][K] bf16.
// 32x32 LDS tile, grid (N/32, K/32).
// ---------------------------------------------------------------------------
__global__ __launch_bounds__(256) void split_tr(const float* __restrict__ Wsrc,
        ushort* __restrict__ th, ushort* __restrict__ tl, int K, int N)
{
    __shared__ float tile[32][33];
    const int nb = blockIdx.x * 32, kb = blockIdx.y * 32;
    const int t = threadIdx.x;
    {
        int r = t >> 3, c4 = (t & 7) * 4;
        float4 v = *(const float4*)&Wsrc[(size_t)(kb + r) * N + nb + c4];
        tile[r][c4 + 0] = v.x; tile[r][c4 + 1] = v.y;
        tile[r][c4 + 2] = v.z; tile[r][c4 + 3] = v.w;
    }
    __syncthreads();
    {
        int n = t >> 3, k4 = (t & 7) * 4;
        float a0 = tile[k4 + 0][n], a1 = tile[k4 + 1][n];
        float a2 = tile[k4 + 2][n], a3 = tile[k4 + 3][n];
        ushort4 h, l;
        h.x = f2bf_rne(a0); l.x = f2bf_rne(a0 - bf2f(h.x));
        h.y = f2bf_rne(a1); l.y = f2bf_rne(a1 - bf2f(h.y));
        h.z = f2bf_rne(a2); l.z = f2bf_rne(a2 - bf2f(h.z));
        h.w = f2bf_rne(a3); l.w = f2bf_rne(a3 - bf2f(h.w));
        size_t o = (size_t)(nb + n) * K + kb + k4;
        *(ushort4*)&th[o] = h;
        *(ushort4*)&tl[o] = l;
    }
}

// ---------------------------------------------------------------------------
// MFMA GEMM, split-bf16 operands.
//   A planes: [M][Kd] row-major bf16 (hi,lo).
//   B planes: [N][Kd] row-major bf16 (TRANSPOSED weights — B^T layout).
//   C = A@B + bias, optional ReLU; out fp32 OR split planes (OUT_SPLIT).
// 128x128 tile, BK=32 (= one mfma_f32_16x16x32_bf16 K-depth), 256 thr = 4
// waves (2x2), 64x64 per wave = 4x4 frags, 3 MFMA per frag pair (hi/lo terms).
// LDS rows padded to 40 ushorts (80B): conflict-free b128 frag reads/writes.
// Upgrade path (next rounds): global_load_lds staging, 8-phase schedule.
// ---------------------------------------------------------------------------
#define LDSP 40

template<bool RELU, bool OUT_SPLIT>
__global__ __launch_bounds__(256) void gemm_mfma(
        const ushort* __restrict__ Ah, const ushort* __restrict__ Al,
        const ushort* __restrict__ Bh, const ushort* __restrict__ Bl,
        const float* __restrict__ bias,
        float* __restrict__ C, ushort* __restrict__ Ch, ushort* __restrict__ Cl,
        int M, int N, int Kd)
{
    __shared__ __align__(16) ushort sAh[128 * LDSP];
    __shared__ __align__(16) ushort sAl[128 * LDSP];
    __shared__ __align__(16) ushort sBh[128 * LDSP];
    __shared__ __align__(16) ushort sBl[128 * LDSP];

    const int t    = threadIdx.x;
    const int lane = t & 63;
    const int w    = t >> 6;
    const int wr   = (w >> 1) * 64;   // wave row offset in tile
    const int wc   = (w & 1) * 64;    // wave col offset in tile
    const int brow = blockIdx.y * 128;
    const int bcol = blockIdx.x * 128;

    f32x4_t acc[4][4];
    #pragma unroll
    for (int i = 0; i < 4; ++i)
        #pragma unroll
        for (int j = 0; j < 4; ++j)
            acc[i][j] = (f32x4_t){0.f, 0.f, 0.f, 0.f};

    const int fr  = lane & 15;        // frag row/col within 16
    const int kb8 = (lane >> 4) * 8;  // k-element base for this lane

    for (int k0 = 0; k0 < Kd; k0 += 32) {
        __syncthreads();              // protect prior iteration's readers
        #pragma unroll
        for (int c = 0; c < 2; ++c) { // stage 8KB/plane: thread -> 16B chunk
            int F   = c * 4096 + t * 16;   // flat byte offset in (unpadded) tile
            int row = F >> 6;              // 64B of data per row
            int eo  = (F & 63) >> 1;       // element offset in row
            size_t gA = (size_t)(brow + row) * Kd + k0 + eo;
            size_t gB = (size_t)(bcol + row) * Kd + k0 + eo;
            int li = row * LDSP + eo;
            *(bf16x8_t*)&sAh[li] = *(const bf16x8_t*)&Ah[gA];
            *(bf16x8_t*)&sAl[li] = *(const bf16x8_t*)&Al[gA];
            *(bf16x8_t*)&sBh[li] = *(const bf16x8_t*)&Bh[gB];
            *(bf16x8_t*)&sBl[li] = *(const bf16x8_t*)&Bl[gB];
        }
        __syncthreads();

        bf16x8_t ah[4], al[4], bh[4], bl[4];
        #pragma unroll
        for (int i = 0; i < 4; ++i) {
            int m = wr + i * 16 + fr;
            ah[i] = *(const bf16x8_t*)&sAh[m * LDSP + kb8];
            al[i] = *(const bf16x8_t*)&sAl[m * LDSP + kb8];
        }
        #pragma unroll
        for (int j = 0; j < 4; ++j) {
            int n = wc + j * 16 + fr;
            bh[j] = *(const bf16x8_t*)&sBh[n * LDSP + kb8];
            bl[j] = *(const bf16x8_t*)&sBl[n * LDSP + kb8];
        }
        #pragma unroll
        for (int i = 0; i < 4; ++i)
            #pragma unroll
            for (int j = 0; j < 4; ++j) {
                acc[i][j] = __builtin_amdgcn_mfma_f32_16x16x32_bf16(ah[i], bh[j], acc[i][j], 0, 0, 0);
                acc[i][j] = __builtin_amdgcn_mfma_f32_16x16x32_bf16(ah[i], bl[j], acc[i][j], 0, 0, 0);
                acc[i][j] = __builtin_amdgcn_mfma_f32_16x16x32_bf16(al[i], bh[j], acc[i][j], 0, 0, 0);
            }
    }

    // epilogue — C/D layout (verified): col = lane&15, row = 4*(lane>>4)+reg
    const int cl = lane & 15;
    const int rq = (lane >> 4) * 4;
    #pragma unroll
    for (int j = 0; j < 4; ++j) {
        int col = bcol + wc + j * 16 + cl;
        float bv = bias[col];
        #pragma unroll
        for (int i = 0; i < 4; ++i) {
            #pragma unroll
            for (int r = 0; r < 4; ++r) {
                int row = brow + wr + i * 16 + rq + r;
                float v = acc[i][j][r] + bv;
                if (RELU) v = fmaxf(v, 0.f);
                if (OUT_SPLIT) {
                    ushort h = f2bf_rne(v);
                    Ch[(size_t)row * N + col] = h;
                    Cl[(size_t)row * N + col] = f2bf_rne(v - bf2f(h));
                } else {
                    C[(size_t)row * N + col] = v;
                }
            }
        }
    }
}

// ---------------------------------------------------------------------------
// Flash attention (fp32 vector, online softmax). One thread per q-row.
// Writes output directly as split-bf16 planes (next consumer is a GEMM).
// ---------------------------------------------------------------------------
__global__ __launch_bounds__(256) void flash_attn(const float* __restrict__ q,
        const float* __restrict__ k, const float* __restrict__ v,
        ushort* __restrict__ Oh, ushort* __restrict__ Ol)
{
    const int b  = blockIdx.z;
    const int h  = blockIdx.y;
    const int qi = blockIdx.x * 256 + threadIdx.x;

    const float* qrow = q + ((size_t)(b * NQ_) + qi) * D_ + h * DH_;
    float qr[DH_];
    #pragma unroll
    for (int d = 0; d < DH_; d += 4) {
        float4 f = *(const float4*)&qrow[d];
        qr[d] = f.x; qr[d+1] = f.y; qr[d+2] = f.z; qr[d+3] = f.w;
    }

    float acc[DH_] = {};
    float m = -INFINITY, l = 0.0f;

    __shared__ float ks[16][DH_];
    __shared__ float vs[16][DH_];

    for (int kt = 0; kt < NK_; kt += 16) {
        __syncthreads();
        {
            const int t = threadIdx.x;
            #pragma unroll
            for (int e = t; e < 16 * DH_; e += 256) {
                int r = e >> 6, c = e & 63;
                size_t ga = ((size_t)(b * NK_) + kt + r) * D_ + h * DH_ + c;
                ks[r][c] = k[ga];
                vs[r][c] = v[ga];
            }
        }
        __syncthreads();

        float s[16];
        #pragma unroll
        for (int kk = 0; kk < 16; ++kk) {
            float dot = 0.0f;
            #pragma unroll
            for (int d4 = 0; d4 < DH_ / 4; ++d4) {
                float4 kv = *(const float4*)&ks[kk][d4 * 4];
                dot = fmaf(qr[d4*4+0], kv.x, dot);
                dot = fmaf(qr[d4*4+1], kv.y, dot);
                dot = fmaf(qr[d4*4+2], kv.z, dot);
                dot = fmaf(qr[d4*4+3], kv.w, dot);
            }
            s[kk] = dot * SCALE_;
        }

        float tmax = s[0];
        #pragma unroll
        for (int kk = 1; kk < 16; ++kk) tmax = fmaxf(tmax, s[kk]);
        float mnew = fmaxf(m, tmax);
        float corr = __expf(m - mnew);
        l *= corr;
        #pragma unroll
        for (int d = 0; d < DH_; ++d) acc[d] *= corr;

        #pragma unroll
        for (int kk = 0; kk < 16; ++kk) {
            float p = __expf(s[kk] - mnew);
            l += p;
            #pragma unroll
            for (int d4 = 0; d4 < DH_ / 4; ++d4) {
                float4 vv = *(const float4*)&vs[kk][d4 * 4];
                acc[d4*4+0] = fmaf(p, vv.x, acc[d4*4+0]);
                acc[d4*4+1] = fmaf(p, vv.y, acc[d4*4+1]);
                acc[d4*4+2] = fmaf(p, vv.z, acc[d4*4+2]);
                acc[d4*4+3] = fmaf(p, vv.w, acc[d4*4+3]);
            }
        }
        m = mnew;
    }

    float inv = 1.0f / l;
    size_t obase = ((size_t)(b * NQ_) + qi) * D_ + h * DH_;
    #pragma unroll
    for (int d = 0; d < DH_; d += 4) {
        ushort4 hh, ll;
        float v0 = acc[d+0]*inv, v1 = acc[d+1]*inv, v2 = acc[d+2]*inv, v3 = acc[d+3]*inv;
        hh.x = f2bf_rne(v0); ll.x = f2bf_rne(v0 - bf2f(hh.x));
        hh.y = f2bf_rne(v1); ll.y = f2bf_rne(v1 - bf2f(hh.y));
        hh.z = f2bf_rne(v2); ll.z = f2bf_rne(v2 - bf2f(hh.z));
        hh.w = f2bf_rne(v3); ll.w = f2bf_rne(v3 - bf2f(hh.w));
        *(ushort4*)&Oh[obase + d] = hh;
        *(ushort4*)&Ol[obase + d] = ll;
    }
}

// ---------------------------------------------------------------------------
// out[row] = LayerNorm(a[row] + r[row]) * g + be.
// ---------------------------------------------------------------------------
__global__ __launch_bounds__(256) void add_ln(const float* __restrict__ a,
        const float* __restrict__ r, const float* __restrict__ g,
        const float* __restrict__ be, float* __restrict__ out)
{
    const int row = blockIdx.x;
    const int t = threadIdx.x;
    float vals[4];
    float s1 = 0.0f, s2 = 0.0f;
    #pragma unroll
    for (int i = 0; i < 4; ++i) {
        int col = t + i * 256;
        float vv = a[(size_t)row * D_ + col] + r[(size_t)row * D_ + col];
        vals[i] = vv;
        s1 += vv;
        s2 += vv * vv;
    }
    #pragma unroll
    for (int off = 32; off > 0; off >>= 1) {
        s1 += __shfl_down(s1, off, 64);
        s2 += __shfl_down(s2, off, 64);
    }
    __shared__ float p1[4], p2[4];
    const int wave = t >> 6;
    if ((t & 63) == 0) { p1[wave] = s1; p2[wave] = s2; }
    __syncthreads();
    s1 = p1[0] + p1[1] + p1[2] + p1[3];
    s2 = p2[0] + p2[1] + p2[2] + p2[3];
    const float mean = s1 * (1.0f / D_);
    const float var  = s2 * (1.0f / D_) - mean * mean;
    const float rstd = rsqrtf(var + LN_EPS_);
    #pragma unroll
    for (int i = 0; i < 4; ++i) {
        int col = t + i * 256;
        out[(size_t)row * D_ + col] = (vals[i] - mean) * rstd * g[col] + be[col];
    }
}

// ---------------------------------------------------------------------------
// Workspace layout (byte offsets, MB). Extent 112MB.
//  [0,64):  early: Qpair[0,16) Kpair[16,32) Wq..Wo pairs[32,48) aOpair[48,64)
//           late:  Hid planes (GEMM5 out, all prior tenants dead)
//  [64,80): qp -> oprj -> W1 pair -> Y
//  [80,96): kp -> X fp32 (live to end)
//  [96,112): vp -> X pair -> W2 pair
// ---------------------------------------------------------------------------
extern "C" void kernel_launch(void* const* d_in, const int* in_sizes, int n_in,
                              void* d_out, int out_size, void* d_ws, size_t ws_size,
                              hipStream_t stream)
{
    const float* Q   = (const float*)d_in[0];
    const float* K   = (const float*)d_in[1];
    const float* Wq  = (const float*)d_in[2];
    const float* bq  = (const float*)d_in[3];
    const float* Wk  = (const float*)d_in[4];
    const float* bk  = (const float*)d_in[5];
    const float* Wv  = (const float*)d_in[6];
    const float* bv  = (const float*)d_in[7];
    const float* Wo  = (const float*)d_in[8];
    const float* bo  = (const float*)d_in[9];
    const float* W1  = (const float*)d_in[10];
    const float* b1  = (const float*)d_in[11];
    const float* W2  = (const float*)d_in[12];
    const float* b2  = (const float*)d_in[13];
    const float* g0  = (const float*)d_in[14];
    const float* be0 = (const float*)d_in[15];
    const float* g1  = (const float*)d_in[16];
    const float* be1 = (const float*)d_in[17];

    unsigned char* Wb = (unsigned char*)d_ws;
    const size_t MBy = 1ull << 20;

    ushort* Qh  = (ushort*)(Wb +  0 * MBy);
    ushort* Ql  = (ushort*)(Wb +  8 * MBy);
    ushort* Kh  = (ushort*)(Wb + 16 * MBy);
    ushort* Kl  = (ushort*)(Wb + 24 * MBy);
    ushort* Wqh = (ushort*)(Wb + 32 * MBy);
    ushort* Wql = (ushort*)(Wb + 34 * MBy);
    ushort* Wkh = (ushort*)(Wb + 36 * MBy);
    ushort* Wkl = (ushort*)(Wb + 38 * MBy);
    ushort* Wvh = (ushort*)(Wb + 40 * MBy);
    ushort* Wvl = (ushort*)(Wb + 42 * MBy);
    ushort* Woh = (ushort*)(Wb + 44 * MBy);
    ushort* Wol = (ushort*)(Wb + 46 * MBy);
    ushort* aOh = (ushort*)(Wb + 48 * MBy);
    ushort* aOl = (ushort*)(Wb + 56 * MBy);
    ushort* Hih = (ushort*)(Wb +  0 * MBy);   // 32MB
    ushort* Hil = (ushort*)(Wb + 32 * MBy);   // 32MB

    float*  qp   = (float*)(Wb + 64 * MBy);
    float*  kp   = (float*)(Wb + 80 * MBy);
    float*  vp   = (float*)(Wb + 96 * MBy);
    float*  oprj = qp;                         // qp dead after attention
    float*  Xf   = kp;                         // kp dead after attention
    ushort* Xh   = (ushort*)(Wb +  96 * MBy);  // vp dead after attention
    ushort* Xl   = (ushort*)(Wb + 104 * MBy);
    ushort* W1h  = (ushort*)(Wb + 64 * MBy);   // oprj dead after LN0
    ushort* W1l  = (ushort*)(Wb + 72 * MBy);
    ushort* W2h  = (ushort*)(Wb +  96 * MBy);  // X pair dead after GEMM5
    ushort* W2l  = (ushort*)(Wb + 104 * MBy);
    float*  Y    = (float*)(Wb + 64 * MBy);    // W1 pair dead after GEMM5

    const int M = B_ * NQ_;                    // 4096
    const int n4act = M * D_ / 4;              // 1M float4 per 16MB tensor
    dim3 blk(256);

    // split inputs + weights
    split_rows<<<n4act / 256, blk, 0, stream>>>(Q, Qh, Ql, n4act);
    split_rows<<<n4act / 256, blk, 0, stream>>>(K, Kh, Kl, n4act);
    split_tr<<<dim3(D_/32, D_/32), blk, 0, stream>>>(Wq, Wqh, Wql, D_, D_);
    split_tr<<<dim3(D_/32, D_/32), blk, 0, stream>>>(Wk, Wkh, Wkl, D_, D_);
    split_tr<<<dim3(D_/32, D_/32), blk, 0, stream>>>(Wv, Wvh, Wvl, D_, D_);
    split_tr<<<dim3(D_/32, D_/32), blk, 0, stream>>>(Wo, Woh, Wol, D_, D_);

    dim3 gD(D_ / 128, M / 128);      // (8,32)
    dim3 gF(DFF_ / 128, M / 128);    // (32,32)

    // q/k/v projections
    gemm_mfma<false,false><<<gD, blk, 0, stream>>>(Qh, Ql, Wqh, Wql, bq, qp, nullptr, nullptr, M, D_, D_);
    gemm_mfma<false,false><<<gD, blk, 0, stream>>>(Kh, Kl, Wkh, Wkl, bk, kp, nullptr, nullptr, M, D_, D_);
    gemm_mfma<false,false><<<gD, blk, 0, stream>>>(Kh, Kl, Wvh, Wvl, bv, vp, nullptr, nullptr, M, D_, D_);

    // attention -> split planes
    flash_attn<<<dim3(NQ_ / 256, H_, B_), blk, 0, stream>>>(qp, kp, vp, aOh, aOl);

    // output projection + LN0
    gemm_mfma<false,false><<<gD, blk, 0, stream>>>(aOh, aOl, Woh, Wol, bo, oprj, nullptr, nullptr, M, D_, D_);
    add_ln<<<M, blk, 0, stream>>>(oprj, Q, g0, be0, Xf);

    // FFN
    split_rows<<<n4act / 256, blk, 0, stream>>>(Xf, Xh, Xl, n4act);
    split_tr<<<dim3(DFF_/32, D_/32), blk, 0, stream>>>(W1, W1h, W1l, D_, DFF_);
    gemm_mfma<true,true><<<gF, blk, 0, stream>>>(Xh, Xl, W1h, W1l, b1, nullptr, Hih, Hil, M, DFF_, D_);
    split_tr<<<dim3(D_/32, DFF_/32), blk, 0, stream>>>(W2, W2h, W2l, DFF_, D_);
    gemm_mfma<false,false><<<gD, blk, 0, stream>>>(Hih, Hil, W2h, W2l, b2, Y, nullptr, nullptr, M, D_, DFF_);
    add_ln<<<M, blk, 0, stream>>>(Y, Xf, g1, be1, (float*)d_out);
}

// Round 4
// 614.737 us; speedup vs baseline: 1.7418x; 1.7418x over previous
//
#include <hip/hip_runtime.h>
#include <math.h>

#define B_   4
#define NQ_  1024
#define NK_  1024
#define D_   1024
#define H_   16
#define DH_  64
#define DFF_ 4096
#define SCALE_ (1.0f/32.0f)   // 1/sqrt(D)
#define LN_EPS_ 1e-5f

typedef __attribute__((ext_vector_type(8))) short bf16x8_t;  // 8 bf16 = 4 VGPR
typedef __attribute__((ext_vector_type(4))) float f32x4_t;

__device__ __forceinline__ ushort f2bf_rne(float x) {
    unsigned u = __float_as_uint(x);
    unsigned r = (u + 0x7FFFu + ((u >> 16) & 1u)) >> 16;
    return (ushort)r;
}
__device__ __forceinline__ float bf2f(ushort h) {
    return __uint_as_float(((unsigned)h) << 16);
}

// ---------------------------------------------------------------------------
// fp32 -> (hi,lo) bf16 planes.
// ---------------------------------------------------------------------------
__global__ __launch_bounds__(256) void split_rows(const float* __restrict__ src,
        ushort* __restrict__ hi, ushort* __restrict__ lo, int n4)
{
    int i = blockIdx.x * 256 + threadIdx.x;
    if (i >= n4) return;
    float4 v = ((const float4*)src)[i];
    ushort4 h, l;
    h.x = f2bf_rne(v.x); l.x = f2bf_rne(v.x - bf2f(h.x));
    h.y = f2bf_rne(v.y); l.y = f2bf_rne(v.y - bf2f(h.y));
    h.z = f2bf_rne(v.z); l.z = f2bf_rne(v.z - bf2f(h.z));
    h.w = f2bf_rne(v.w); l.w = f2bf_rne(v.w - bf2f(h.w));
    ((ushort4*)hi)[i] = h;
    ((ushort4*)lo)[i] = l;
}

// ---------------------------------------------------------------------------
// Weight split + transpose: W[K][N] fp32 -> planes Wt[N][K] bf16.
// ---------------------------------------------------------------------------
__global__ __launch_bounds__(256) void split_tr(const float* __restrict__ Wsrc,
        ushort* __restrict__ th, ushort* __restrict__ tl, int K, int N)
{
    __shared__ float tile[32][33];
    const int nb = blockIdx.x * 32, kb = blockIdx.y * 32;
    const int t = threadIdx.x;
    {
        int r = t >> 3, c4 = (t & 7) * 4;
        float4 v = *(const float4*)&Wsrc[(size_t)(kb + r) * N + nb + c4];
        tile[r][c4 + 0] = v.x; tile[r][c4 + 1] = v.y;
        tile[r][c4 + 2] = v.z; tile[r][c4 + 3] = v.w;
    }
    __syncthreads();
    {
        int n = t >> 3, k4 = (t & 7) * 4;
        float a0 = tile[k4 + 0][n], a1 = tile[k4 + 1][n];
        float a2 = tile[k4 + 2][n], a3 = tile[k4 + 3][n];
        ushort4 h, l;
        h.x = f2bf_rne(a0); l.x = f2bf_rne(a0 - bf2f(h.x));
        h.y = f2bf_rne(a1); l.y = f2bf_rne(a1 - bf2f(h.y));
        h.z = f2bf_rne(a2); l.z = f2bf_rne(a2 - bf2f(h.z));
        h.w = f2bf_rne(a3); l.w = f2bf_rne(a3 - bf2f(h.w));
        size_t o = (size_t)(nb + n) * K + kb + k4;
        *(ushort4*)&th[o] = h;
        *(ushort4*)&tl[o] = l;
    }
}

// ---------------------------------------------------------------------------
// MFMA GEMM, split-bf16 operands (validated round 3).
// OMODE: 0 = fp32 out, 1 = split planes out, 2 = hi-only bf16 out.
// ---------------------------------------------------------------------------
#define LDSP 40

template<bool RELU, int OMODE>
__global__ __launch_bounds__(256) void gemm_mfma(
        const ushort* __restrict__ Ah, const ushort* __restrict__ Al,
        const ushort* __restrict__ Bh, const ushort* __restrict__ Bl,
        const float* __restrict__ bias,
        float* __restrict__ C, ushort* __restrict__ Ch, ushort* __restrict__ Cl,
        int M, int N, int Kd)
{
    __shared__ __align__(16) ushort sAh[128 * LDSP];
    __shared__ __align__(16) ushort sAl[128 * LDSP];
    __shared__ __align__(16) ushort sBh[128 * LDSP];
    __shared__ __align__(16) ushort sBl[128 * LDSP];

    const int t    = threadIdx.x;
    const int lane = t & 63;
    const int w    = t >> 6;
    const int wr   = (w >> 1) * 64;
    const int wc   = (w & 1) * 64;
    const int brow = blockIdx.y * 128;
    const int bcol = blockIdx.x * 128;

    f32x4_t acc[4][4];
    #pragma unroll
    for (int i = 0; i < 4; ++i)
        #pragma unroll
        for (int j = 0; j < 4; ++j)
            acc[i][j] = (f32x4_t){0.f, 0.f, 0.f, 0.f};

    const int fr  = lane & 15;
    const int kb8 = (lane >> 4) * 8;

    for (int k0 = 0; k0 < Kd; k0 += 32) {
        __syncthreads();
        #pragma unroll
        for (int c = 0; c < 2; ++c) {
            int F   = c * 4096 + t * 16;
            int row = F >> 6;
            int eo  = (F & 63) >> 1;
            size_t gA = (size_t)(brow + row) * Kd + k0 + eo;
            size_t gB = (size_t)(bcol + row) * Kd + k0 + eo;
            int li = row * LDSP + eo;
            *(bf16x8_t*)&sAh[li] = *(const bf16x8_t*)&Ah[gA];
            *(bf16x8_t*)&sAl[li] = *(const bf16x8_t*)&Al[gA];
            *(bf16x8_t*)&sBh[li] = *(const bf16x8_t*)&Bh[gB];
            *(bf16x8_t*)&sBl[li] = *(const bf16x8_t*)&Bl[gB];
        }
        __syncthreads();

        bf16x8_t ah[4], al[4], bh[4], bl[4];
        #pragma unroll
        for (int i = 0; i < 4; ++i) {
            int m = wr + i * 16 + fr;
            ah[i] = *(const bf16x8_t*)&sAh[m * LDSP + kb8];
            al[i] = *(const bf16x8_t*)&sAl[m * LDSP + kb8];
        }
        #pragma unroll
        for (int j = 0; j < 4; ++j) {
            int n = wc + j * 16 + fr;
            bh[j] = *(const bf16x8_t*)&sBh[n * LDSP + kb8];
            bl[j] = *(const bf16x8_t*)&sBl[n * LDSP + kb8];
        }
        #pragma unroll
        for (int i = 0; i < 4; ++i)
            #pragma unroll
            for (int j = 0; j < 4; ++j) {
                acc[i][j] = __builtin_amdgcn_mfma_f32_16x16x32_bf16(ah[i], bh[j], acc[i][j], 0, 0, 0);
                acc[i][j] = __builtin_amdgcn_mfma_f32_16x16x32_bf16(ah[i], bl[j], acc[i][j], 0, 0, 0);
                acc[i][j] = __builtin_amdgcn_mfma_f32_16x16x32_bf16(al[i], bh[j], acc[i][j], 0, 0, 0);
            }
    }

    const int cl = lane & 15;
    const int rq = (lane >> 4) * 4;
    #pragma unroll
    for (int j = 0; j < 4; ++j) {
        int col = bcol + wc + j * 16 + cl;
        float bv = bias[col];
        #pragma unroll
        for (int i = 0; i < 4; ++i) {
            #pragma unroll
            for (int r = 0; r < 4; ++r) {
                int row = brow + wr + i * 16 + rq + r;
                float v = acc[i][j][r] + bv;
                if (RELU) v = fmaxf(v, 0.f);
                if (OMODE == 1) {
                    ushort h = f2bf_rne(v);
                    Ch[(size_t)row * N + col] = h;
                    Cl[(size_t)row * N + col] = f2bf_rne(v - bf2f(h));
                } else if (OMODE == 2) {
                    Ch[(size_t)row * N + col] = f2bf_rne(v);
                } else {
                    C[(size_t)row * N + col] = v;
                }
            }
        }
    }
}

// ---------------------------------------------------------------------------
// MFMA flash attention. Grid 1024 blocks (XCD-chunked bh mapping), 4 waves.
// Each wave: 16 q-rows. KVBLK=32. q/k/v are bf16 planes [B*N][D], head at
// h*64. S = Q·K^T via mfma (A=Q frag, B=K rows); softmax via 16-lane
// shfl_xor reduce; P -> per-wave LDS (bf16) -> A-frag; O += P·V via
// V^T staged in LDS (stride 40, write map kv=t&31 for <=2-way banks).
// Output written as split-bf16 planes (feeds Wo GEMM).
// ---------------------------------------------------------------------------
__global__ __launch_bounds__(256) void flash_attn_mfma(
        const ushort* __restrict__ qh, const ushort* __restrict__ kh,
        const ushort* __restrict__ vh,
        ushort* __restrict__ Oh, ushort* __restrict__ Ol)
{
    __shared__ __align__(16) ushort sk[32 * 72];
    __shared__ __align__(16) ushort svt[64 * 40];
    __shared__ __align__(16) ushort pbuf[4][16 * 40];

    // XCD-chunked mapping: xcd = bid%8 handles bh in [8*xcd, 8*xcd+8)
    const int bid  = blockIdx.x;
    const int slot = bid >> 3;               // 0..127
    const int bh   = (bid & 7) * 8 + (slot >> 4);
    const int qt   = slot & 15;
    const int b    = bh >> 4;
    const int h    = bh & 15;
    const int qb   = qt * 64;

    const int t = threadIdx.x, lane = t & 63, w = t >> 6;
    const int l15 = lane & 15, g = lane >> 4;

    // Q fragments (held for whole kernel)
    bf16x8_t qf[2];
    {
        size_t qrow = ((size_t)(b * NQ_) + qb + w * 16 + l15) * D_ + h * DH_;
        qf[0] = *(const bf16x8_t*)&qh[qrow + 0  + 8 * g];
        qf[1] = *(const bf16x8_t*)&qh[qrow + 32 + 8 * g];
    }

    f32x4_t acc[4];
    #pragma unroll
    for (int dt = 0; dt < 4; ++dt) acc[dt] = (f32x4_t){0.f, 0.f, 0.f, 0.f};
    float m[4]    = {-INFINITY, -INFINITY, -INFINITY, -INFINITY};
    float lsum[4] = {0.f, 0.f, 0.f, 0.f};

    // staging maps
    const int kkv = t >> 3,  kds = (t & 7) * 8;   // K: b128 write
    const int vkv = t & 31,  vds = (t >> 5) * 8;  // V: scatter, kv spreads banks
    const size_t kvbase = (size_t)(b * NK_) * D_ + h * DH_;

    for (int kt = 0; kt < NK_; kt += 32) {
        __syncthreads();
        {   // stage K tile [32][64] -> sk (stride 72)
            bf16x8_t kk = *(const bf16x8_t*)&kh[kvbase + (size_t)(kt + kkv) * D_ + kds];
            *(bf16x8_t*)&sk[kkv * 72 + kds] = kk;
            // stage V transposed -> svt[d][kv] (stride 40)
            bf16x8_t vv = *(const bf16x8_t*)&vh[kvbase + (size_t)(kt + vkv) * D_ + vds];
            #pragma unroll
            for (int j = 0; j < 8; ++j)
                svt[(vds + j) * 40 + vkv] = (ushort)vv[j];
        }
        __syncthreads();

        // QK^T: two 16x16 S-tiles (kv 0-15, 16-31)
        f32x4_t s0 = (f32x4_t){0.f,0.f,0.f,0.f};
        f32x4_t s1 = (f32x4_t){0.f,0.f,0.f,0.f};
        #pragma unroll
        for (int c = 0; c < 2; ++c) {
            bf16x8_t k0 = *(const bf16x8_t*)&sk[(l15     ) * 72 + 32 * c + 8 * g];
            bf16x8_t k1 = *(const bf16x8_t*)&sk[(l15 + 16) * 72 + 32 * c + 8 * g];
            s0 = __builtin_amdgcn_mfma_f32_16x16x32_bf16(qf[c], k0, s0, 0, 0, 0);
            s1 = __builtin_amdgcn_mfma_f32_16x16x32_bf16(qf[c], k1, s1, 0, 0, 0);
        }

        // online softmax (rows q = 4g+r live in 16-lane group g)
        float p0[4], p1[4], corr[4];
        #pragma unroll
        for (int r = 0; r < 4; ++r) {
            float e0 = s0[r] * SCALE_, e1 = s1[r] * SCALE_;
            float tm = fmaxf(e0, e1);
            tm = fmaxf(tm, __shfl_xor(tm, 1, 64));
            tm = fmaxf(tm, __shfl_xor(tm, 2, 64));
            tm = fmaxf(tm, __shfl_xor(tm, 4, 64));
            tm = fmaxf(tm, __shfl_xor(tm, 8, 64));
            float mn = fmaxf(m[r], tm);
            corr[r] = __expf(m[r] - mn);
            p0[r] = __expf(e0 - mn);
            p1[r] = __expf(e1 - mn);
            float ps = p0[r] + p1[r];
            ps += __shfl_xor(ps, 1, 64);
            ps += __shfl_xor(ps, 2, 64);
            ps += __shfl_xor(ps, 4, 64);
            ps += __shfl_xor(ps, 8, 64);
            lsum[r] = lsum[r] * corr[r] + ps;
            m[r] = mn;
        }
        #pragma unroll
        for (int dt = 0; dt < 4; ++dt)
            #pragma unroll
            for (int r = 0; r < 4; ++r)
                acc[dt][r] *= corr[r];

        // P -> per-wave LDS (bf16), then A-frag
        ushort* pw = &pbuf[w][0];
        #pragma unroll
        for (int r = 0; r < 4; ++r) {
            pw[(4 * g + r) * 40 + l15     ] = f2bf_rne(p0[r]);
            pw[(4 * g + r) * 40 + l15 + 16] = f2bf_rne(p1[r]);
        }
        bf16x8_t pa = *(const bf16x8_t*)&pw[l15 * 40 + 8 * g];

        // PV: O[q][d] += P·V, 4 d-tiles
        #pragma unroll
        for (int dt = 0; dt < 4; ++dt) {
            bf16x8_t vf = *(const bf16x8_t*)&svt[(16 * dt + l15) * 40 + 8 * g];
            acc[dt] = __builtin_amdgcn_mfma_f32_16x16x32_bf16(pa, vf, acc[dt], 0, 0, 0);
        }
    }

    // epilogue: O/l -> split planes
    float inv[4];
    #pragma unroll
    for (int r = 0; r < 4; ++r) inv[r] = 1.0f / lsum[r];
    #pragma unroll
    for (int dt = 0; dt < 4; ++dt) {
        #pragma unroll
        for (int r = 0; r < 4; ++r) {
            int row = b * NQ_ + qb + w * 16 + 4 * g + r;
            int col = h * DH_ + 16 * dt + l15;
            float v = acc[dt][r] * inv[r];
            ushort hh = f2bf_rne(v);
            Oh[(size_t)row * D_ + col] = hh;
            Ol[(size_t)row * D_ + col] = f2bf_rne(v - bf2f(hh));
        }
    }
}

// ---------------------------------------------------------------------------
// out[row] = LayerNorm(a[row] + r[row]) * g + be.
// ---------------------------------------------------------------------------
__global__ __launch_bounds__(256) void add_ln(const float* __restrict__ a,
        const float* __restrict__ r, const float* __restrict__ g,
        const float* __restrict__ be, float* __restrict__ out)
{
    const int row = blockIdx.x;
    const int t = threadIdx.x;
    float vals[4];
    float s1 = 0.0f, s2 = 0.0f;
    #pragma unroll
    for (int i = 0; i < 4; ++i) {
        int col = t + i * 256;
        float vv = a[(size_t)row * D_ + col] + r[(size_t)row * D_ + col];
        vals[i] = vv;
        s1 += vv;
        s2 += vv * vv;
    }
    #pragma unroll
    for (int off = 32; off > 0; off >>= 1) {
        s1 += __shfl_down(s1, off, 64);
        s2 += __shfl_down(s2, off, 64);
    }
    __shared__ float p1[4], p2[4];
    const int wave = t >> 6;
    if ((t & 63) == 0) { p1[wave] = s1; p2[wave] = s2; }
    __syncthreads();
    s1 = p1[0] + p1[1] + p1[2] + p1[3];
    s2 = p2[0] + p2[1] + p2[2] + p2[3];
    const float mean = s1 * (1.0f / D_);
    const float var  = s2 * (1.0f / D_) - mean * mean;
    const float rstd = rsqrtf(var + LN_EPS_);
    #pragma unroll
    for (int i = 0; i < 4; ++i) {
        int col = t + i * 256;
        out[(size_t)row * D_ + col] = (vals[i] - mean) * rstd * g[col] + be[col];
    }
}

// ---------------------------------------------------------------------------
// Workspace (MB offsets), peak 112MB:
//  Qh 0 Ql 8 Kh 16 Kl 24 | Wq 32/34 Wk 36/38 Wv 40/42 Wo 44/46 |
//  qh 48 kh 56 vh 64 | aOh 72 aOl 80
//  then: oprj f32 @16, Xf f32 @0, Xh 48 Xl 56, W1h 64 W1l 72,
//        Hih @80(32MB), Hil @16(32MB), W2h 48 W2l 56, Y f32 @64.
// ---------------------------------------------------------------------------
extern "C" void kernel_launch(void* const* d_in, const int* in_sizes, int n_in,
                              void* d_out, int out_size, void* d_ws, size_t ws_size,
                              hipStream_t stream)
{
    const float* Q   = (const float*)d_in[0];
    const float* K   = (const float*)d_in[1];
    const float* Wq  = (const float*)d_in[2];
    const float* bq  = (const float*)d_in[3];
    const float* Wk  = (const float*)d_in[4];
    const float* bk  = (const float*)d_in[5];
    const float* Wv  = (const float*)d_in[6];
    const float* bv  = (const float*)d_in[7];
    const float* Wo  = (const float*)d_in[8];
    const float* bo  = (const float*)d_in[9];
    const float* W1  = (const float*)d_in[10];
    const float* b1  = (const float*)d_in[11];
    const float* W2  = (const float*)d_in[12];
    const float* b2  = (const float*)d_in[13];
    const float* g0  = (const float*)d_in[14];
    const float* be0 = (const float*)d_in[15];
    const float* g1  = (const float*)d_in[16];
    const float* be1 = (const float*)d_in[17];

    unsigned char* Wb = (unsigned char*)d_ws;
    const size_t MBy = 1ull << 20;

    ushort* Qh  = (ushort*)(Wb +  0 * MBy);
    ushort* Ql  = (ushort*)(Wb +  8 * MBy);
    ushort* Kh  = (ushort*)(Wb + 16 * MBy);
    ushort* Kl  = (ushort*)(Wb + 24 * MBy);
    ushort* Wqh = (ushort*)(Wb + 32 * MBy);
    ushort* Wql = (ushort*)(Wb + 34 * MBy);
    ushort* Wkh = (ushort*)(Wb + 36 * MBy);
    ushort* Wkl = (ushort*)(Wb + 38 * MBy);
    ushort* Wvh = (ushort*)(Wb + 40 * MBy);
    ushort* Wvl = (ushort*)(Wb + 42 * MBy);
    ushort* Woh = (ushort*)(Wb + 44 * MBy);
    ushort* Wol = (ushort*)(Wb + 46 * MBy);
    ushort* qhp = (ushort*)(Wb + 48 * MBy);
    ushort* khp = (ushort*)(Wb + 56 * MBy);
    ushort* vhp = (ushort*)(Wb + 64 * MBy);
    ushort* aOh = (ushort*)(Wb + 72 * MBy);
    ushort* aOl = (ushort*)(Wb + 80 * MBy);

    float*  oprj = (float*)(Wb + 16 * MBy);
    float*  Xf   = (float*)(Wb +  0 * MBy);
    ushort* Xh   = (ushort*)(Wb + 48 * MBy);
    ushort* Xl   = (ushort*)(Wb + 56 * MBy);
    ushort* W1h  = (ushort*)(Wb + 64 * MBy);
    ushort* W1l  = (ushort*)(Wb + 72 * MBy);
    ushort* Hih  = (ushort*)(Wb + 80 * MBy);   // 32MB
    ushort* Hil  = (ushort*)(Wb + 16 * MBy);   // 32MB
    ushort* W2h  = (ushort*)(Wb + 48 * MBy);
    ushort* W2l  = (ushort*)(Wb + 56 * MBy);
    float*  Y    = (float*)(Wb + 64 * MBy);

    const int M = B_ * NQ_;
    const int n4act = M * D_ / 4;
    dim3 blk(256);
    dim3 gD(D_ / 128, M / 128);
    dim3 gF(DFF_ / 128, M / 128);

    split_rows<<<n4act / 256, blk, 0, stream>>>(Q, Qh, Ql, n4act);
    split_rows<<<n4act / 256, blk, 0, stream>>>(K, Kh, Kl, n4act);
    split_tr<<<dim3(D_/32, D_/32), blk, 0, stream>>>(Wq, Wqh, Wql, D_, D_);
    split_tr<<<dim3(D_/32, D_/32), blk, 0, stream>>>(Wk, Wkh, Wkl, D_, D_);
    split_tr<<<dim3(D_/32, D_/32), blk, 0, stream>>>(Wv, Wvh, Wvl, D_, D_);
    split_tr<<<dim3(D_/32, D_/32), blk, 0, stream>>>(Wo, Woh, Wol, D_, D_);

    // projections -> bf16 hi planes
    gemm_mfma<false,2><<<gD, blk, 0, stream>>>(Qh, Ql, Wqh, Wql, bq, nullptr, qhp, nullptr, M, D_, D_);
    gemm_mfma<false,2><<<gD, blk, 0, stream>>>(Kh, Kl, Wkh, Wkl, bk, nullptr, khp, nullptr, M, D_, D_);
    gemm_mfma<false,2><<<gD, blk, 0, stream>>>(Kh, Kl, Wvh, Wvl, bv, nullptr, vhp, nullptr, M, D_, D_);

    flash_attn_mfma<<<dim3(1024), blk, 0, stream>>>(qhp, khp, vhp, aOh, aOl);

    gemm_mfma<false,0><<<gD, blk, 0, stream>>>(aOh, aOl, Woh, Wol, bo, oprj, nullptr, nullptr, M, D_, D_);
    add_ln<<<M, blk, 0, stream>>>(oprj, Q, g0, be0, Xf);

    split_rows<<<n4act / 256, blk, 0, stream>>>(Xf, Xh, Xl, n4act);
    split_tr<<<dim3(DFF_/32, D_/32), blk, 0, stream>>>(W1, W1h, W1l, D_, DFF_);
    gemm_mfma<true,1><<<gF, blk, 0, stream>>>(Xh, Xl, W1h, W1l, b1, nullptr, Hih, Hil, M, DFF_, D_);
    split_tr<<<dim3(D_/32, DFF_/32), blk, 0, stream>>>(W2, W2h, W2l, DFF_, D_);
    gemm_mfma<false,0><<<gD, blk, 0, stream>>>(Hih, Hil, W2h, W2l, b2, Y, nullptr, nullptr, M, D_, DFF_);
    add_ln<<<M, blk, 0, stream>>>(Y, Xf, g1, be1, (float*)d_out);
}

// Round 5
// 596.489 us; speedup vs baseline: 1.7951x; 1.0306x over previous
//
#include <hip/hip_runtime.h>
#include <math.h>

#define B_   4
#define NQ_  1024
#define NK_  1024
#define D_   1024
#define H_   16
#define DH_  64
#define DFF_ 4096
#define SCALE_ (1.0f/32.0f)   // 1/sqrt(D)
#define LN_EPS_ 1e-5f

typedef __attribute__((ext_vector_type(8))) short bf16x8_t;  // 8 bf16 = 4 VGPR
typedef __attribute__((ext_vector_type(4))) float f32x4_t;

__device__ __forceinline__ ushort f2bf_rne(float x) {
    unsigned u = __float_as_uint(x);
    unsigned r = (u + 0x7FFFu + ((u >> 16) & 1u)) >> 16;
    return (ushort)r;
}
__device__ __forceinline__ float bf2f(ushort h) {
    return __uint_as_float(((unsigned)h) << 16);
}

// async global->LDS, 16B per lane. LDS dest = wave-uniform base + lane*16.
__device__ __forceinline__ void gl_lds16(const ushort* g, ushort* l) {
    __builtin_amdgcn_global_load_lds(
        (const __attribute__((address_space(1))) unsigned int*)g,
        (__attribute__((address_space(3))) unsigned int*)l, 16, 0, 0);
}

// ---------------------------------------------------------------------------
// fp32 -> (hi,lo) bf16 planes.
// ---------------------------------------------------------------------------
__global__ __launch_bounds__(256) void split_rows(const float* __restrict__ src,
        ushort* __restrict__ hi, ushort* __restrict__ lo, int n4)
{
    int i = blockIdx.x * 256 + threadIdx.x;
    if (i >= n4) return;
    float4 v = ((const float4*)src)[i];
    ushort4 h, l;
    h.x = f2bf_rne(v.x); l.x = f2bf_rne(v.x - bf2f(h.x));
    h.y = f2bf_rne(v.y); l.y = f2bf_rne(v.y - bf2f(h.y));
    h.z = f2bf_rne(v.z); l.z = f2bf_rne(v.z - bf2f(h.z));
    h.w = f2bf_rne(v.w); l.w = f2bf_rne(v.w - bf2f(h.w));
    ((ushort4*)hi)[i] = h;
    ((ushort4*)lo)[i] = l;
}

// ---------------------------------------------------------------------------
// Weight split + transpose: W[K][N] fp32 -> planes Wt[N][K] bf16.
// ---------------------------------------------------------------------------
__global__ __launch_bounds__(256) void split_tr(const float* __restrict__ Wsrc,
        ushort* __restrict__ th, ushort* __restrict__ tl, int K, int N)
{
    __shared__ float tile[32][33];
    const int nb = blockIdx.x * 32, kb = blockIdx.y * 32;
    const int t = threadIdx.x;
    {
        int r = t >> 3, c4 = (t & 7) * 4;
        float4 v = *(const float4*)&Wsrc[(size_t)(kb + r) * N + nb + c4];
        tile[r][c4 + 0] = v.x; tile[r][c4 + 1] = v.y;
        tile[r][c4 + 2] = v.z; tile[r][c4 + 3] = v.w;
    }
    __syncthreads();
    {
        int n = t >> 3, k4 = (t & 7) * 4;
        float a0 = tile[k4 + 0][n], a1 = tile[k4 + 1][n];
        float a2 = tile[k4 + 2][n], a3 = tile[k4 + 3][n];
        ushort4 h, l;
        h.x = f2bf_rne(a0); l.x = f2bf_rne(a0 - bf2f(h.x));
        h.y = f2bf_rne(a1); l.y = f2bf_rne(a1 - bf2f(h.y));
        h.z = f2bf_rne(a2); l.z = f2bf_rne(a2 - bf2f(h.z));
        h.w = f2bf_rne(a3); l.w = f2bf_rne(a3 - bf2f(h.w));
        size_t o = (size_t)(nb + n) * K + kb + k4;
        *(ushort4*)&th[o] = h;
        *(ushort4*)&tl[o] = l;
    }
}

// ---------------------------------------------------------------------------
// MFMA GEMM, split-bf16 operands. m97 structure: linear LDS [128][32] per
// plane, global_load_lds width-16 staging (one plane per wave, 8 issues),
// 2-barrier K-loop. XCD-chunked block swizzle for L2 locality.
// OMODE: 0 = fp32 out, 1 = split planes out, 2 = hi-only bf16 out.
// ---------------------------------------------------------------------------
template<bool RELU, int OMODE>
__global__ __launch_bounds__(256) void gemm_mfma(
        const ushort* __restrict__ Ah, const ushort* __restrict__ Al,
        const ushort* __restrict__ Bh, const ushort* __restrict__ Bl,
        const float* __restrict__ bias,
        float* __restrict__ C, ushort* __restrict__ Ch, ushort* __restrict__ Cl,
        int M, int N, int Kd)
{
    __shared__ __align__(16) ushort sAll[4][128 * 32];   // 32KB, linear

    const int t    = threadIdx.x;
    const int lane = t & 63;
    const int w    = t >> 6;
    const int wr   = (w >> 1) * 64;
    const int wc   = (w & 1) * 64;

    // bijective XCD-chunked swizzle (nwg % 8 == 0 for all our grids)
    const int nx  = gridDim.x;
    const int lin = blockIdx.y * nx + blockIdx.x;
    const int cpx = (nx * gridDim.y) >> 3;
    const int swz = (lin & 7) * cpx + (lin >> 3);
    const int brow = (swz / nx) * 128;
    const int bcol = (swz % nx) * 128;

    f32x4_t acc[4][4];
    #pragma unroll
    for (int i = 0; i < 4; ++i)
        #pragma unroll
        for (int j = 0; j < 4; ++j)
            acc[i][j] = (f32x4_t){0.f, 0.f, 0.f, 0.f};

    const int fr  = lane & 15;
    const int kb8 = (lane >> 4) * 8;

    // staging map: wave w owns plane w; lane covers row (lane>>2), 8 elems
    const ushort* gplane = (w == 0) ? Ah : (w == 1) ? Al : (w == 2) ? Bh : Bl;
    const int     rb     = (w < 2) ? brow : bcol;
    const size_t  grow   = (size_t)(rb + (lane >> 2)) * Kd + (lane & 3) * 8;
    ushort*       lplane = &sAll[w][0];

    for (int k0 = 0; k0 < Kd; k0 += 32) {
        __syncthreads();               // prior iteration's readers done
        #pragma unroll
        for (int i = 0; i < 8; ++i)    // 8 x 1KB = one [16][32] row-chunk each
            gl_lds16(gplane + grow + (size_t)(16 * i) * Kd + k0, lplane + i * 512);
        __syncthreads();               // drains vmcnt -> tile visible

        bf16x8_t ah[4], al[4], bh[4], bl[4];
        #pragma unroll
        for (int i = 0; i < 4; ++i) {
            int m = wr + i * 16 + fr;
            ah[i] = *(const bf16x8_t*)&sAll[0][m * 32 + kb8];
            al[i] = *(const bf16x8_t*)&sAll[1][m * 32 + kb8];
        }
        #pragma unroll
        for (int j = 0; j < 4; ++j) {
            int n = wc + j * 16 + fr;
            bh[j] = *(const bf16x8_t*)&sAll[2][n * 32 + kb8];
            bl[j] = *(const bf16x8_t*)&sAll[3][n * 32 + kb8];
        }
        #pragma unroll
        for (int i = 0; i < 4; ++i)
            #pragma unroll
            for (int j = 0; j < 4; ++j) {
                acc[i][j] = __builtin_amdgcn_mfma_f32_16x16x32_bf16(ah[i], bh[j], acc[i][j], 0, 0, 0);
                acc[i][j] = __builtin_amdgcn_mfma_f32_16x16x32_bf16(ah[i], bl[j], acc[i][j], 0, 0, 0);
                acc[i][j] = __builtin_amdgcn_mfma_f32_16x16x32_bf16(al[i], bh[j], acc[i][j], 0, 0, 0);
            }
    }

    const int cl = lane & 15;
    const int rq = (lane >> 4) * 4;
    #pragma unroll
    for (int j = 0; j < 4; ++j) {
        int col = bcol + wc + j * 16 + cl;
        float bv = bias[col];
        #pragma unroll
        for (int i = 0; i < 4; ++i) {
            #pragma unroll
            for (int r = 0; r < 4; ++r) {
                int row = brow + wr + i * 16 + rq + r;
                float v = acc[i][j][r] + bv;
                if (RELU) v = fmaxf(v, 0.f);
                if (OMODE == 1) {
                    ushort h = f2bf_rne(v);
                    Ch[(size_t)row * N + col] = h;
                    Cl[(size_t)row * N + col] = f2bf_rne(v - bf2f(h));
                } else if (OMODE == 2) {
                    Ch[(size_t)row * N + col] = f2bf_rne(v);
                } else {
                    C[(size_t)row * N + col] = v;
                }
            }
        }
    }
}

// ---------------------------------------------------------------------------
// MFMA flash attention (validated round 4). 1024 blocks, 4 waves, QBLK=64,
// KVBLK=32; online softmax via 16-lane shfl_xor; output split planes.
// ---------------------------------------------------------------------------
__global__ __launch_bounds__(256) void flash_attn_mfma(
        const ushort* __restrict__ qh, const ushort* __restrict__ kh,
        const ushort* __restrict__ vh,
        ushort* __restrict__ Oh, ushort* __restrict__ Ol)
{
    __shared__ __align__(16) ushort sk[32 * 72];
    __shared__ __align__(16) ushort svt[64 * 40];
    __shared__ __align__(16) ushort pbuf[4][16 * 40];

    const int bid  = blockIdx.x;
    const int slot = bid >> 3;
    const int bh   = (bid & 7) * 8 + (slot >> 4);
    const int qt   = slot & 15;
    const int b    = bh >> 4;
    const int h    = bh & 15;
    const int qb   = qt * 64;

    const int t = threadIdx.x, lane = t & 63, w = t >> 6;
    const int l15 = lane & 15, g = lane >> 4;

    bf16x8_t qf[2];
    {
        size_t qrow = ((size_t)(b * NQ_) + qb + w * 16 + l15) * D_ + h * DH_;
        qf[0] = *(const bf16x8_t*)&qh[qrow + 0  + 8 * g];
        qf[1] = *(const bf16x8_t*)&qh[qrow + 32 + 8 * g];
    }

    f32x4_t acc[4];
    #pragma unroll
    for (int dt = 0; dt < 4; ++dt) acc[dt] = (f32x4_t){0.f, 0.f, 0.f, 0.f};
    float m[4]    = {-INFINITY, -INFINITY, -INFINITY, -INFINITY};
    float lsum[4] = {0.f, 0.f, 0.f, 0.f};

    const int kkv = t >> 3,  kds = (t & 7) * 8;
    const int vkv = t & 31,  vds = (t >> 5) * 8;
    const size_t kvbase = (size_t)(b * NK_) * D_ + h * DH_;

    for (int kt = 0; kt < NK_; kt += 32) {
        __syncthreads();
        {
            bf16x8_t kk = *(const bf16x8_t*)&kh[kvbase + (size_t)(kt + kkv) * D_ + kds];
            *(bf16x8_t*)&sk[kkv * 72 + kds] = kk;
            bf16x8_t vv = *(const bf16x8_t*)&vh[kvbase + (size_t)(kt + vkv) * D_ + vds];
            #pragma unroll
            for (int j = 0; j < 8; ++j)
                svt[(vds + j) * 40 + vkv] = (ushort)vv[j];
        }
        __syncthreads();

        f32x4_t s0 = (f32x4_t){0.f,0.f,0.f,0.f};
        f32x4_t s1 = (f32x4_t){0.f,0.f,0.f,0.f};
        #pragma unroll
        for (int c = 0; c < 2; ++c) {
            bf16x8_t k0 = *(const bf16x8_t*)&sk[(l15     ) * 72 + 32 * c + 8 * g];
            bf16x8_t k1 = *(const bf16x8_t*)&sk[(l15 + 16) * 72 + 32 * c + 8 * g];
            s0 = __builtin_amdgcn_mfma_f32_16x16x32_bf16(qf[c], k0, s0, 0, 0, 0);
            s1 = __builtin_amdgcn_mfma_f32_16x16x32_bf16(qf[c], k1, s1, 0, 0, 0);
        }

        float p0[4], p1[4], corr[4];
        #pragma unroll
        for (int r = 0; r < 4; ++r) {
            float e0 = s0[r] * SCALE_, e1 = s1[r] * SCALE_;
            float tm = fmaxf(e0, e1);
            tm = fmaxf(tm, __shfl_xor(tm, 1, 64));
            tm = fmaxf(tm, __shfl_xor(tm, 2, 64));
            tm = fmaxf(tm, __shfl_xor(tm, 4, 64));
            tm = fmaxf(tm, __shfl_xor(tm, 8, 64));
            float mn = fmaxf(m[r], tm);
            corr[r] = __expf(m[r] - mn);
            p0[r] = __expf(e0 - mn);
            p1[r] = __expf(e1 - mn);
            float ps = p0[r] + p1[r];
            ps += __shfl_xor(ps, 1, 64);
            ps += __shfl_xor(ps, 2, 64);
            ps += __shfl_xor(ps, 4, 64);
            ps += __shfl_xor(ps, 8, 64);
            lsum[r] = lsum[r] * corr[r] + ps;
            m[r] = mn;
        }
        #pragma unroll
        for (int dt = 0; dt < 4; ++dt)
            #pragma unroll
            for (int r = 0; r < 4; ++r)
                acc[dt][r] *= corr[r];

        ushort* pw = &pbuf[w][0];
        #pragma unroll
        for (int r = 0; r < 4; ++r) {
            pw[(4 * g + r) * 40 + l15     ] = f2bf_rne(p0[r]);
            pw[(4 * g + r) * 40 + l15 + 16] = f2bf_rne(p1[r]);
        }
        bf16x8_t pa = *(const bf16x8_t*)&pw[l15 * 40 + 8 * g];

        #pragma unroll
        for (int dt = 0; dt < 4; ++dt) {
            bf16x8_t vf = *(const bf16x8_t*)&svt[(16 * dt + l15) * 40 + 8 * g];
            acc[dt] = __builtin_amdgcn_mfma_f32_16x16x32_bf16(pa, vf, acc[dt], 0, 0, 0);
        }
    }

    float inv[4];
    #pragma unroll
    for (int r = 0; r < 4; ++r) inv[r] = 1.0f / lsum[r];
    #pragma unroll
    for (int dt = 0; dt < 4; ++dt) {
        #pragma unroll
        for (int r = 0; r < 4; ++r) {
            int row = b * NQ_ + qb + w * 16 + 4 * g + r;
            int col = h * DH_ + 16 * dt + l15;
            float v = acc[dt][r] * inv[r];
            ushort hh = f2bf_rne(v);
            Oh[(size_t)row * D_ + col] = hh;
            Ol[(size_t)row * D_ + col] = f2bf_rne(v - bf2f(hh));
        }
    }
}

// ---------------------------------------------------------------------------
// out[row] = LayerNorm(a[row] + r[row]) * g + be.
// ---------------------------------------------------------------------------
__global__ __launch_bounds__(256) void add_ln(const float* __restrict__ a,
        const float* __restrict__ r, const float* __restrict__ g,
        const float* __restrict__ be, float* __restrict__ out)
{
    const int row = blockIdx.x;
    const int t = threadIdx.x;
    float vals[4];
    float s1 = 0.0f, s2 = 0.0f;
    #pragma unroll
    for (int i = 0; i < 4; ++i) {
        int col = t + i * 256;
        float vv = a[(size_t)row * D_ + col] + r[(size_t)row * D_ + col];
        vals[i] = vv;
        s1 += vv;
        s2 += vv * vv;
    }
    #pragma unroll
    for (int off = 32; off > 0; off >>= 1) {
        s1 += __shfl_down(s1, off, 64);
        s2 += __shfl_down(s2, off, 64);
    }
    __shared__ float p1[4], p2[4];
    const int wave = t >> 6;
    if ((t & 63) == 0) { p1[wave] = s1; p2[wave] = s2; }
    __syncthreads();
    s1 = p1[0] + p1[1] + p1[2] + p1[3];
    s2 = p2[0] + p2[1] + p2[2] + p2[3];
    const float mean = s1 * (1.0f / D_);
    const float var  = s2 * (1.0f / D_) - mean * mean;
    const float rstd = rsqrtf(var + LN_EPS_);
    #pragma unroll
    for (int i = 0; i < 4; ++i) {
        int col = t + i * 256;
        out[(size_t)row * D_ + col] = (vals[i] - mean) * rstd * g[col] + be[col];
    }
}

// ---------------------------------------------------------------------------
extern "C" void kernel_launch(void* const* d_in, const int* in_sizes, int n_in,
                              void* d_out, int out_size, void* d_ws, size_t ws_size,
                              hipStream_t stream)
{
    const float* Q   = (const float*)d_in[0];
    const float* K   = (const float*)d_in[1];
    const float* Wq  = (const float*)d_in[2];
    const float* bq  = (const float*)d_in[3];
    const float* Wk  = (const float*)d_in[4];
    const float* bk  = (const float*)d_in[5];
    const float* Wv  = (const float*)d_in[6];
    const float* bv  = (const float*)d_in[7];
    const float* Wo  = (const float*)d_in[8];
    const float* bo  = (const float*)d_in[9];
    const float* W1  = (const float*)d_in[10];
    const float* b1  = (const float*)d_in[11];
    const float* W2  = (const float*)d_in[12];
    const float* b2  = (const float*)d_in[13];
    const float* g0  = (const float*)d_in[14];
    const float* be0 = (const float*)d_in[15];
    const float* g1  = (const float*)d_in[16];
    const float* be1 = (const float*)d_in[17];

    unsigned char* Wb = (unsigned char*)d_ws;
    const size_t MBy = 1ull << 20;

    ushort* Qh  = (ushort*)(Wb +  0 * MBy);
    ushort* Ql  = (ushort*)(Wb +  8 * MBy);
    ushort* Kh  = (ushort*)(Wb + 16 * MBy);
    ushort* Kl  = (ushort*)(Wb + 24 * MBy);
    ushort* Wqh = (ushort*)(Wb + 32 * MBy);
    ushort* Wql = (ushort*)(Wb + 34 * MBy);
    ushort* Wkh = (ushort*)(Wb + 36 * MBy);
    ushort* Wkl = (ushort*)(Wb + 38 * MBy);
    ushort* Wvh = (ushort*)(Wb + 40 * MBy);
    ushort* Wvl = (ushort*)(Wb + 42 * MBy);
    ushort* Woh = (ushort*)(Wb + 44 * MBy);
    ushort* Wol = (ushort*)(Wb + 46 * MBy);
    ushort* qhp = (ushort*)(Wb + 48 * MBy);
    ushort* khp = (ushort*)(Wb + 56 * MBy);
    ushort* vhp = (ushort*)(Wb + 64 * MBy);
    ushort* aOh = (ushort*)(Wb + 72 * MBy);
    ushort* aOl = (ushort*)(Wb + 80 * MBy);

    float*  oprj = (float*)(Wb + 16 * MBy);
    float*  Xf   = (float*)(Wb +  0 * MBy);
    ushort* Xh   = (ushort*)(Wb + 48 * MBy);
    ushort* Xl   = (ushort*)(Wb + 56 * MBy);
    ushort* W1h  = (ushort*)(Wb + 64 * MBy);
    ushort* W1l  = (ushort*)(Wb + 72 * MBy);
    ushort* Hih  = (ushort*)(Wb + 80 * MBy);   // 32MB
    ushort* Hil  = (ushort*)(Wb + 16 * MBy);   // 32MB
    ushort* W2h  = (ushort*)(Wb + 48 * MBy);
    ushort* W2l  = (ushort*)(Wb + 56 * MBy);
    float*  Y    = (float*)(Wb + 64 * MBy);

    const int M = B_ * NQ_;
    const int n4act = M * D_ / 4;
    dim3 blk(256);
    dim3 gD(D_ / 128, M / 128);
    dim3 gF(DFF_ / 128, M / 128);

    split_rows<<<n4act / 256, blk, 0, stream>>>(Q, Qh, Ql, n4act);
    split_rows<<<n4act / 256, blk, 0, stream>>>(K, Kh, Kl, n4act);
    split_tr<<<dim3(D_/32, D_/32), blk, 0, stream>>>(Wq, Wqh, Wql, D_, D_);
    split_tr<<<dim3(D_/32, D_/32), blk, 0, stream>>>(Wk, Wkh, Wkl, D_, D_);
    split_tr<<<dim3(D_/32, D_/32), blk, 0, stream>>>(Wv, Wvh, Wvl, D_, D_);
    split_tr<<<dim3(D_/32, D_/32), blk, 0, stream>>>(Wo, Woh, Wol, D_, D_);

    gemm_mfma<false,2><<<gD, blk, 0, stream>>>(Qh, Ql, Wqh, Wql, bq, nullptr, qhp, nullptr, M, D_, D_);
    gemm_mfma<false,2><<<gD, blk, 0, stream>>>(Kh, Kl, Wkh, Wkl, bk, nullptr, khp, nullptr, M, D_, D_);
    gemm_mfma<false,2><<<gD, blk, 0, stream>>>(Kh, Kl, Wvh, Wvl, bv, nullptr, vhp, nullptr, M, D_, D_);

    flash_attn_mfma<<<dim3(1024), blk, 0, stream>>>(qhp, khp, vhp, aOh, aOl);

    gemm_mfma<false,0><<<gD, blk, 0, stream>>>(aOh, aOl, Woh, Wol, bo, oprj, nullptr, nullptr, M, D_, D_);
    add_ln<<<M, blk, 0, stream>>>(oprj, Q, g0, be0, Xf);

    split_rows<<<n4act / 256, blk, 0, stream>>>(Xf, Xh, Xl, n4act);
    split_tr<<<dim3(DFF_/32, D_/32), blk, 0, stream>>>(W1, W1h, W1l, D_, DFF_);
    gemm_mfma<true,1><<<gF, blk, 0, stream>>>(Xh, Xl, W1h, W1l, b1, nullptr, Hih, Hil, M, DFF_, D_);
    split_tr<<<dim3(D_/32, DFF_/32), blk, 0, stream>>>(W2, W2h, W2l, DFF_, D_);
    gemm_mfma<false,0><<<gD, blk, 0, stream>>>(Hih, Hil, W2h, W2l, b2, Y, nullptr, nullptr, M, D_, DFF_);
    add_ln<<<M, blk, 0, stream>>>(Y, Xf, g1, be1, (float*)d_out);
}

// Round 6
// 572.818 us; speedup vs baseline: 1.8693x; 1.0413x over previous
//
#include <hip/hip_runtime.h>
#include <math.h>

#define B_   4
#define NQ_  1024
#define NK_  1024
#define D_   1024
#define H_   16
#define DH_  64
#define DFF_ 4096
#define SCALE_ (1.0f/32.0f)   // 1/sqrt(D)
#define LN_EPS_ 1e-5f

typedef __attribute__((ext_vector_type(8))) short bf16x8_t;  // 8 bf16 = 4 VGPR
typedef __attribute__((ext_vector_type(4))) float f32x4_t;

__device__ __forceinline__ ushort f2bf_rne(float x) {
    unsigned u = __float_as_uint(x);
    unsigned r = (u + 0x7FFFu + ((u >> 16) & 1u)) >> 16;
    return (ushort)r;
}
__device__ __forceinline__ float bf2f(ushort h) {
    return __uint_as_float(((unsigned)h) << 16);
}

// async global->LDS, 16B per lane. LDS dest = wave-uniform base + lane*16.
__device__ __forceinline__ void gl_lds16(const ushort* g, ushort* l) {
    __builtin_amdgcn_global_load_lds(
        (const __attribute__((address_space(1))) unsigned int*)g,
        (__attribute__((address_space(3))) unsigned int*)l, 16, 0, 0);
}

// ---------------------------------------------------------------------------
// fp32 -> (hi,lo) bf16 planes.
// ---------------------------------------------------------------------------
__global__ __launch_bounds__(256) void split_rows(const float* __restrict__ src,
        ushort* __restrict__ hi, ushort* __restrict__ lo, int n4)
{
    int i = blockIdx.x * 256 + threadIdx.x;
    if (i >= n4) return;
    float4 v = ((const float4*)src)[i];
    ushort4 h, l;
    h.x = f2bf_rne(v.x); l.x = f2bf_rne(v.x - bf2f(h.x));
    h.y = f2bf_rne(v.y); l.y = f2bf_rne(v.y - bf2f(h.y));
    h.z = f2bf_rne(v.z); l.z = f2bf_rne(v.z - bf2f(h.z));
    h.w = f2bf_rne(v.w); l.w = f2bf_rne(v.w - bf2f(h.w));
    ((ushort4*)hi)[i] = h;
    ((ushort4*)lo)[i] = l;
}

// ---------------------------------------------------------------------------
// Weight split + transpose: W[K][N] fp32 -> planes Wt[N][K] bf16.
// ---------------------------------------------------------------------------
__global__ __launch_bounds__(256) void split_tr(const float* __restrict__ Wsrc,
        ushort* __restrict__ th, ushort* __restrict__ tl, int K, int N)
{
    __shared__ float tile[32][33];
    const int nb = blockIdx.x * 32, kb = blockIdx.y * 32;
    const int t = threadIdx.x;
    {
        int r = t >> 3, c4 = (t & 7) * 4;
        float4 v = *(const float4*)&Wsrc[(size_t)(kb + r) * N + nb + c4];
        tile[r][c4 + 0] = v.x; tile[r][c4 + 1] = v.y;
        tile[r][c4 + 2] = v.z; tile[r][c4 + 3] = v.w;
    }
    __syncthreads();
    {
        int n = t >> 3, k4 = (t & 7) * 4;
        float a0 = tile[k4 + 0][n], a1 = tile[k4 + 1][n];
        float a2 = tile[k4 + 2][n], a3 = tile[k4 + 3][n];
        ushort4 h, l;
        h.x = f2bf_rne(a0); l.x = f2bf_rne(a0 - bf2f(h.x));
        h.y = f2bf_rne(a1); l.y = f2bf_rne(a1 - bf2f(h.y));
        h.z = f2bf_rne(a2); l.z = f2bf_rne(a2 - bf2f(h.z));
        h.w = f2bf_rne(a3); l.w = f2bf_rne(a3 - bf2f(h.w));
        size_t o = (size_t)(nb + n) * K + kb + k4;
        *(ushort4*)&th[o] = h;
        *(ushort4*)&tl[o] = l;
    }
}

// ---------------------------------------------------------------------------
// MFMA GEMM body, split-bf16 operands. m97 structure + LDS XOR swizzle:
//   LDS dest linear (global_load_lds requirement), global SOURCE pre-swizzled
//   per-lane (srcslot = (l&3)^((l>>3)&3), lane-constant), reads use
//   slot' = g ^ ((fr>>1)&3)  -> 16-lane read aliasing period 8 = 2-way (free).
// OMODE: 0 = fp32 out, 1 = split planes out, 2 = hi-only bf16 out.
// ---------------------------------------------------------------------------
template<bool RELU, int OMODE>
__device__ __forceinline__ void gemm_body(
        const ushort* __restrict__ Ah, const ushort* __restrict__ Al,
        const ushort* __restrict__ Bh, const ushort* __restrict__ Bl,
        const float* __restrict__ bias,
        float* __restrict__ C, ushort* __restrict__ Ch, ushort* __restrict__ Cl,
        int M, int N, int Kd, int brow, int bcol)
{
    __shared__ __align__(16) ushort sAll[4][128 * 32];   // 32KB, linear

    const int t    = threadIdx.x;
    const int lane = t & 63;
    const int w    = t >> 6;
    const int wr   = (w >> 1) * 64;
    const int wc   = (w & 1) * 64;

    f32x4_t acc[4][4];
    #pragma unroll
    for (int i = 0; i < 4; ++i)
        #pragma unroll
        for (int j = 0; j < 4; ++j)
            acc[i][j] = (f32x4_t){0.f, 0.f, 0.f, 0.f};

    const int fr = lane & 15;
    const int g  = lane >> 4;
    const int sS = ((g ^ ((fr >> 1) & 3)) << 3);   // swizzled k-slot (ushorts)

    // staging: wave w owns plane w; lane covers row (lane>>2), swizzled slot
    const ushort* gplane = (w == 0) ? Ah : (w == 1) ? Al : (w == 2) ? Bh : Bl;
    const int     rb     = (w < 2) ? brow : bcol;
    const size_t  grow   = (size_t)(rb + (lane >> 2)) * Kd
                         + (((lane & 3) ^ ((lane >> 3) & 3)) << 3);
    ushort*       lplane = &sAll[w][0];

    for (int k0 = 0; k0 < Kd; k0 += 32) {
        __syncthreads();               // prior iteration's readers done
        #pragma unroll
        for (int i = 0; i < 8; ++i)    // 8 x 1KB = one [16][32] row-chunk each
            gl_lds16(gplane + grow + (size_t)(16 * i) * Kd + k0, lplane + i * 512);
        __syncthreads();               // drains vmcnt -> tile visible

        bf16x8_t ah[4], al[4], bh[4], bl[4];
        #pragma unroll
        for (int i = 0; i < 4; ++i) {
            int m = wr + i * 16 + fr;
            ah[i] = *(const bf16x8_t*)&sAll[0][m * 32 + sS];
            al[i] = *(const bf16x8_t*)&sAll[1][m * 32 + sS];
        }
        #pragma unroll
        for (int j = 0; j < 4; ++j) {
            int n = wc + j * 16 + fr;
            bh[j] = *(const bf16x8_t*)&sAll[2][n * 32 + sS];
            bl[j] = *(const bf16x8_t*)&sAll[3][n * 32 + sS];
        }
        #pragma unroll
        for (int i = 0; i < 4; ++i)
            #pragma unroll
            for (int j = 0; j < 4; ++j) {
                acc[i][j] = __builtin_amdgcn_mfma_f32_16x16x32_bf16(ah[i], bh[j], acc[i][j], 0, 0, 0);
                acc[i][j] = __builtin_amdgcn_mfma_f32_16x16x32_bf16(ah[i], bl[j], acc[i][j], 0, 0, 0);
                acc[i][j] = __builtin_amdgcn_mfma_f32_16x16x32_bf16(al[i], bh[j], acc[i][j], 0, 0, 0);
            }
    }

    const int cl = lane & 15;
    const int rq = (lane >> 4) * 4;
    #pragma unroll
    for (int j = 0; j < 4; ++j) {
        int col = bcol + wc + j * 16 + cl;
        float bv = bias[col];
        #pragma unroll
        for (int i = 0; i < 4; ++i) {
            #pragma unroll
            for (int r = 0; r < 4; ++r) {
                int row = brow + wr + i * 16 + rq + r;
                float v = acc[i][j][r] + bv;
                if (RELU) v = fmaxf(v, 0.f);
                if (OMODE == 1) {
                    ushort h = f2bf_rne(v);
                    Ch[(size_t)row * N + col] = h;
                    Cl[(size_t)row * N + col] = f2bf_rne(v - bf2f(h));
                } else if (OMODE == 2) {
                    Ch[(size_t)row * N + col] = f2bf_rne(v);
                } else {
                    C[(size_t)row * N + col] = v;
                }
            }
        }
    }
}

// bijective XCD-chunked swizzle (nwg % 8 == 0 for all our grids)
__device__ __forceinline__ void swz_block(int& brow, int& bcol) {
    const int nx  = gridDim.x;
    const int lin = blockIdx.y * nx + blockIdx.x;
    const int cpx = (nx * gridDim.y) >> 3;
    const int swz = (lin & 7) * cpx + (lin >> 3);
    brow = (swz / nx) * 128;
    bcol = (swz % nx) * 128;
}

template<bool RELU, int OMODE>
__global__ __launch_bounds__(256) void gemm_mfma(
        const ushort* __restrict__ Ah, const ushort* __restrict__ Al,
        const ushort* __restrict__ Bh, const ushort* __restrict__ Bl,
        const float* __restrict__ bias,
        float* __restrict__ C, ushort* __restrict__ Ch, ushort* __restrict__ Cl,
        int M, int N, int Kd)
{
    int brow, bcol;
    swz_block(brow, bcol);
    gemm_body<RELU, OMODE>(Ah, Al, Bh, Bl, bias, C, Ch, Cl, M, N, Kd, brow, bcol);
}

// q/k/v projections fused into one dispatch (grid.z = 3 -> 768 blocks, 3/CU)
struct QkvArgs {
    const ushort* Ah[3]; const ushort* Al[3];
    const ushort* Bh[3]; const ushort* Bl[3];
    const float*  bias[3];
    ushort*       Co[3];
};

__global__ __launch_bounds__(256) void gemm_qkv(QkvArgs qa, int M, int N, int Kd)
{
    int brow, bcol;
    swz_block(brow, bcol);
    const int z = blockIdx.z;
    gemm_body<false, 2>(qa.Ah[z], qa.Al[z], qa.Bh[z], qa.Bl[z], qa.bias[z],
                        nullptr, qa.Co[z], nullptr, M, N, Kd, brow, bcol);
}

// ---------------------------------------------------------------------------
// MFMA flash attention (validated round 4). 1024 blocks, 4 waves, QBLK=64,
// KVBLK=32; online softmax via 16-lane shfl_xor; output split planes.
// ---------------------------------------------------------------------------
__global__ __launch_bounds__(256) void flash_attn_mfma(
        const ushort* __restrict__ qh, const ushort* __restrict__ kh,
        const ushort* __restrict__ vh,
        ushort* __restrict__ Oh, ushort* __restrict__ Ol)
{
    __shared__ __align__(16) ushort sk[32 * 72];
    __shared__ __align__(16) ushort svt[64 * 40];
    __shared__ __align__(16) ushort pbuf[4][16 * 40];

    const int bid  = blockIdx.x;
    const int slot = bid >> 3;
    const int bh   = (bid & 7) * 8 + (slot >> 4);
    const int qt   = slot & 15;
    const int b    = bh >> 4;
    const int h    = bh & 15;
    const int qb   = qt * 64;

    const int t = threadIdx.x, lane = t & 63, w = t >> 6;
    const int l15 = lane & 15, g = lane >> 4;

    bf16x8_t qf[2];
    {
        size_t qrow = ((size_t)(b * NQ_) + qb + w * 16 + l15) * D_ + h * DH_;
        qf[0] = *(const bf16x8_t*)&qh[qrow + 0  + 8 * g];
        qf[1] = *(const bf16x8_t*)&qh[qrow + 32 + 8 * g];
    }

    f32x4_t acc[4];
    #pragma unroll
    for (int dt = 0; dt < 4; ++dt) acc[dt] = (f32x4_t){0.f, 0.f, 0.f, 0.f};
    float m[4]    = {-INFINITY, -INFINITY, -INFINITY, -INFINITY};
    float lsum[4] = {0.f, 0.f, 0.f, 0.f};

    const int kkv = t >> 3,  kds = (t & 7) * 8;
    const int vkv = t & 31,  vds = (t >> 5) * 8;
    const size_t kvbase = (size_t)(b * NK_) * D_ + h * DH_;

    for (int kt = 0; kt < NK_; kt += 32) {
        __syncthreads();
        {
            bf16x8_t kk = *(const bf16x8_t*)&kh[kvbase + (size_t)(kt + kkv) * D_ + kds];
            *(bf16x8_t*)&sk[kkv * 72 + kds] = kk;
            bf16x8_t vv = *(const bf16x8_t*)&vh[kvbase + (size_t)(kt + vkv) * D_ + vds];
            #pragma unroll
            for (int j = 0; j < 8; ++j)
                svt[(vds + j) * 40 + vkv] = (ushort)vv[j];
        }
        __syncthreads();

        f32x4_t s0 = (f32x4_t){0.f,0.f,0.f,0.f};
        f32x4_t s1 = (f32x4_t){0.f,0.f,0.f,0.f};
        #pragma unroll
        for (int c = 0; c < 2; ++c) {
            bf16x8_t k0 = *(const bf16x8_t*)&sk[(l15     ) * 72 + 32 * c + 8 * g];
            bf16x8_t k1 = *(const bf16x8_t*)&sk[(l15 + 16) * 72 + 32 * c + 8 * g];
            s0 = __builtin_amdgcn_mfma_f32_16x16x32_bf16(qf[c], k0, s0, 0, 0, 0);
            s1 = __builtin_amdgcn_mfma_f32_16x16x32_bf16(qf[c], k1, s1, 0, 0, 0);
        }

        float p0[4], p1[4], corr[4];
        #pragma unroll
        for (int r = 0; r < 4; ++r) {
            float e0 = s0[r] * SCALE_, e1 = s1[r] * SCALE_;
            float tm = fmaxf(e0, e1);
            tm = fmaxf(tm, __shfl_xor(tm, 1, 64));
            tm = fmaxf(tm, __shfl_xor(tm, 2, 64));
            tm = fmaxf(tm, __shfl_xor(tm, 4, 64));
            tm = fmaxf(tm, __shfl_xor(tm, 8, 64));
            float mn = fmaxf(m[r], tm);
            corr[r] = __expf(m[r] - mn);
            p0[r] = __expf(e0 - mn);
            p1[r] = __expf(e1 - mn);
            float ps = p0[r] + p1[r];
            ps += __shfl_xor(ps, 1, 64);
            ps += __shfl_xor(ps, 2, 64);
            ps += __shfl_xor(ps, 4, 64);
            ps += __shfl_xor(ps, 8, 64);
            lsum[r] = lsum[r] * corr[r] + ps;
            m[r] = mn;
        }
        #pragma unroll
        for (int dt = 0; dt < 4; ++dt)
            #pragma unroll
            for (int r = 0; r < 4; ++r)
                acc[dt][r] *= corr[r];

        ushort* pw = &pbuf[w][0];
        #pragma unroll
        for (int r = 0; r < 4; ++r) {
            pw[(4 * g + r) * 40 + l15     ] = f2bf_rne(p0[r]);
            pw[(4 * g + r) * 40 + l15 + 16] = f2bf_rne(p1[r]);
        }
        bf16x8_t pa = *(const bf16x8_t*)&pw[l15 * 40 + 8 * g];

        #pragma unroll
        for (int dt = 0; dt < 4; ++dt) {
            bf16x8_t vf = *(const bf16x8_t*)&svt[(16 * dt + l15) * 40 + 8 * g];
            acc[dt] = __builtin_amdgcn_mfma_f32_16x16x32_bf16(pa, vf, acc[dt], 0, 0, 0);
        }
    }

    float inv[4];
    #pragma unroll
    for (int r = 0; r < 4; ++r) inv[r] = 1.0f / lsum[r];
    #pragma unroll
    for (int dt = 0; dt < 4; ++dt) {
        #pragma unroll
        for (int r = 0; r < 4; ++r) {
            int row = b * NQ_ + qb + w * 16 + 4 * g + r;
            int col = h * DH_ + 16 * dt + l15;
            float v = acc[dt][r] * inv[r];
            ushort hh = f2bf_rne(v);
            Oh[(size_t)row * D_ + col] = hh;
            Ol[(size_t)row * D_ + col] = f2bf_rne(v - bf2f(hh));
        }
    }
}

// ---------------------------------------------------------------------------
// out[row] = LayerNorm(a[row] + r[row]) * g + be.
// ---------------------------------------------------------------------------
__global__ __launch_bounds__(256) void add_ln(const float* __restrict__ a,
        const float* __restrict__ r, const float* __restrict__ g,
        const float* __restrict__ be, float* __restrict__ out)
{
    const int row = blockIdx.x;
    const int t = threadIdx.x;
    float vals[4];
    float s1 = 0.0f, s2 = 0.0f;
    #pragma unroll
    for (int i = 0; i < 4; ++i) {
        int col = t + i * 256;
        float vv = a[(size_t)row * D_ + col] + r[(size_t)row * D_ + col];
        vals[i] = vv;
        s1 += vv;
        s2 += vv * vv;
    }
    #pragma unroll
    for (int off = 32; off > 0; off >>= 1) {
        s1 += __shfl_down(s1, off, 64);
        s2 += __shfl_down(s2, off, 64);
    }
    __shared__ float p1[4], p2[4];
    const int wave = t >> 6;
    if ((t & 63) == 0) { p1[wave] = s1; p2[wave] = s2; }
    __syncthreads();
    s1 = p1[0] + p1[1] + p1[2] + p1[3];
    s2 = p2[0] + p2[1] + p2[2] + p2[3];
    const float mean = s1 * (1.0f / D_);
    const float var  = s2 * (1.0f / D_) - mean * mean;
    const float rstd = rsqrtf(var + LN_EPS_);
    #pragma unroll
    for (int i = 0; i < 4; ++i) {
        int col = t + i * 256;
        out[(size_t)row * D_ + col] = (vals[i] - mean) * rstd * g[col] + be[col];
    }
}

// ---------------------------------------------------------------------------
extern "C" void kernel_launch(void* const* d_in, const int* in_sizes, int n_in,
                              void* d_out, int out_size, void* d_ws, size_t ws_size,
                              hipStream_t stream)
{
    const float* Q   = (const float*)d_in[0];
    const float* K   = (const float*)d_in[1];
    const float* Wq  = (const float*)d_in[2];
    const float* bq  = (const float*)d_in[3];
    const float* Wk  = (const float*)d_in[4];
    const float* bk  = (const float*)d_in[5];
    const float* Wv  = (const float*)d_in[6];
    const float* bv  = (const float*)d_in[7];
    const float* Wo  = (const float*)d_in[8];
    const float* bo  = (const float*)d_in[9];
    const float* W1  = (const float*)d_in[10];
    const float* b1  = (const float*)d_in[11];
    const float* W2  = (const float*)d_in[12];
    const float* b2  = (const float*)d_in[13];
    const float* g0  = (const float*)d_in[14];
    const float* be0 = (const float*)d_in[15];
    const float* g1  = (const float*)d_in[16];
    const float* be1 = (const float*)d_in[17];

    unsigned char* Wb = (unsigned char*)d_ws;
    const size_t MBy = 1ull << 20;

    ushort* Qh  = (ushort*)(Wb +  0 * MBy);
    ushort* Ql  = (ushort*)(Wb +  8 * MBy);
    ushort* Kh  = (ushort*)(Wb + 16 * MBy);
    ushort* Kl  = (ushort*)(Wb + 24 * MBy);
    ushort* Wqh = (ushort*)(Wb + 32 * MBy);
    ushort* Wql = (ushort*)(Wb + 34 * MBy);
    ushort* Wkh = (ushort*)(Wb + 36 * MBy);
    ushort* Wkl = (ushort*)(Wb + 38 * MBy);
    ushort* Wvh = (ushort*)(Wb + 40 * MBy);
    ushort* Wvl = (ushort*)(Wb + 42 * MBy);
    ushort* Woh = (ushort*)(Wb + 44 * MBy);
    ushort* Wol = (ushort*)(Wb + 46 * MBy);
    ushort* qhp = (ushort*)(Wb + 48 * MBy);
    ushort* khp = (ushort*)(Wb + 56 * MBy);
    ushort* vhp = (ushort*)(Wb + 64 * MBy);
    ushort* aOh = (ushort*)(Wb + 72 * MBy);
    ushort* aOl = (ushort*)(Wb + 80 * MBy);

    float*  oprj = (float*)(Wb + 16 * MBy);
    float*  Xf   = (float*)(Wb +  0 * MBy);
    ushort* Xh   = (ushort*)(Wb + 48 * MBy);
    ushort* Xl   = (ushort*)(Wb + 56 * MBy);
    ushort* W1h  = (ushort*)(Wb + 64 * MBy);
    ushort* W1l  = (ushort*)(Wb + 72 * MBy);
    ushort* Hih  = (ushort*)(Wb + 80 * MBy);   // 32MB
    ushort* Hil  = (ushort*)(Wb + 16 * MBy);   // 32MB
    ushort* W2h  = (ushort*)(Wb + 48 * MBy);
    ushort* W2l  = (ushort*)(Wb + 56 * MBy);
    float*  Y    = (float*)(Wb + 64 * MBy);

    const int M = B_ * NQ_;
    const int n4act = M * D_ / 4;
    dim3 blk(256);
    dim3 gD(D_ / 128, M / 128);
    dim3 gQKV(D_ / 128, M / 128, 3);
    dim3 gF(DFF_ / 128, M / 128);

    split_rows<<<n4act / 256, blk, 0, stream>>>(Q, Qh, Ql, n4act);
    split_rows<<<n4act / 256, blk, 0, stream>>>(K, Kh, Kl, n4act);
    split_tr<<<dim3(D_/32, D_/32), blk, 0, stream>>>(Wq, Wqh, Wql, D_, D_);
    split_tr<<<dim3(D_/32, D_/32), blk, 0, stream>>>(Wk, Wkh, Wkl, D_, D_);
    split_tr<<<dim3(D_/32, D_/32), blk, 0, stream>>>(Wv, Wvh, Wvl, D_, D_);
    split_tr<<<dim3(D_/32, D_/32), blk, 0, stream>>>(Wo, Woh, Wol, D_, D_);

    QkvArgs qa;
    qa.Ah[0] = Qh;  qa.Al[0] = Ql;  qa.Bh[0] = Wqh; qa.Bl[0] = Wql; qa.bias[0] = bq; qa.Co[0] = qhp;
    qa.Ah[1] = Kh;  qa.Al[1] = Kl;  qa.Bh[1] = Wkh; qa.Bl[1] = Wkl; qa.bias[1] = bk; qa.Co[1] = khp;
    qa.Ah[2] = Kh;  qa.Al[2] = Kl;  qa.Bh[2] = Wvh; qa.Bl[2] = Wvl; qa.bias[2] = bv; qa.Co[2] = vhp;
    gemm_qkv<<<gQKV, blk, 0, stream>>>(qa, M, D_, D_);

    flash_attn_mfma<<<dim3(1024), blk, 0, stream>>>(qhp, khp, vhp, aOh, aOl);

    gemm_mfma<false,0><<<gD, blk, 0, stream>>>(aOh, aOl, Woh, Wol, bo, oprj, nullptr, nullptr, M, D_, D_);
    add_ln<<<M, blk, 0, stream>>>(oprj, Q, g0, be0, Xf);

    split_rows<<<n4act / 256, blk, 0, stream>>>(Xf, Xh, Xl, n4act);
    split_tr<<<dim3(DFF_/32, D_/32), blk, 0, stream>>>(W1, W1h, W1l, D_, DFF_);
    gemm_mfma<true,1><<<gF, blk, 0, stream>>>(Xh, Xl, W1h, W1l, b1, nullptr, Hih, Hil, M, DFF_, D_);
    split_tr<<<dim3(D_/32, DFF_/32), blk, 0, stream>>>(W2, W2h, W2l, DFF_, D_);
    gemm_mfma<false,0><<<gD, blk, 0, stream>>>(Hih, Hil, W2h, W2l, b2, Y, nullptr, nullptr, M, D_, DFF_);
    add_ln<<<M, blk, 0, stream>>>(Y, Xf, g1, be1, (float*)d_out);
}

// Round 7
// 487.849 us; speedup vs baseline: 2.1949x; 1.1742x over previous
//
#include <hip/hip_runtime.h>
#include <math.h>

#define B_   4
#define NQ_  1024
#define NK_  1024
#define D_   1024
#define H_   16
#define DH_  64
#define DFF_ 4096
#define SCALE_ (1.0f/32.0f)   // 1/sqrt(D)
#define LN_EPS_ 1e-5f

typedef __attribute__((ext_vector_type(8))) short bf16x8_t;  // 8 bf16 = 4 VGPR
typedef __attribute__((ext_vector_type(4))) float f32x4_t;

__device__ __forceinline__ ushort f2bf_rne(float x) {
    unsigned u = __float_as_uint(x);
    unsigned r = (u + 0x7FFFu + ((u >> 16) & 1u)) >> 16;
    return (ushort)r;
}
__device__ __forceinline__ float bf2f(ushort h) {
    return __uint_as_float(((unsigned)h) << 16);
}

// async global->LDS, 16B per lane. LDS dest = wave-uniform base + lane*16.
__device__ __forceinline__ void gl_lds16(const ushort* g, ushort* l) {
    __builtin_amdgcn_global_load_lds(
        (const __attribute__((address_space(1))) unsigned int*)g,
        (__attribute__((address_space(3))) unsigned int*)l, 16, 0, 0);
}

// ---------------------------------------------------------------------------
// fp32 -> (hi,lo) bf16 planes.
// ---------------------------------------------------------------------------
__global__ __launch_bounds__(256) void split_rows(const float* __restrict__ src,
        ushort* __restrict__ hi, ushort* __restrict__ lo, int n4)
{
    int i = blockIdx.x * 256 + threadIdx.x;
    if (i >= n4) return;
    float4 v = ((const float4*)src)[i];
    ushort4 h, l;
    h.x = f2bf_rne(v.x); l.x = f2bf_rne(v.x - bf2f(h.x));
    h.y = f2bf_rne(v.y); l.y = f2bf_rne(v.y - bf2f(h.y));
    h.z = f2bf_rne(v.z); l.z = f2bf_rne(v.z - bf2f(h.z));
    h.w = f2bf_rne(v.w); l.w = f2bf_rne(v.w - bf2f(h.w));
    ((ushort4*)hi)[i] = h;
    ((ushort4*)lo)[i] = l;
}

// ---------------------------------------------------------------------------
// Weight split + transpose: W[K][N] fp32 -> planes Wt[N][K] bf16.
// ---------------------------------------------------------------------------
__global__ __launch_bounds__(256) void split_tr(const float* __restrict__ Wsrc,
        ushort* __restrict__ th, ushort* __restrict__ tl, int K, int N)
{
    __shared__ float tile[32][33];
    const int nb = blockIdx.x * 32, kb = blockIdx.y * 32;
    const int t = threadIdx.x;
    {
        int r = t >> 3, c4 = (t & 7) * 4;
        float4 v = *(const float4*)&Wsrc[(size_t)(kb + r) * N + nb + c4];
        tile[r][c4 + 0] = v.x; tile[r][c4 + 1] = v.y;
        tile[r][c4 + 2] = v.z; tile[r][c4 + 3] = v.w;
    }
    __syncthreads();
    {
        int n = t >> 3, k4 = (t & 7) * 4;
        float a0 = tile[k4 + 0][n], a1 = tile[k4 + 1][n];
        float a2 = tile[k4 + 2][n], a3 = tile[k4 + 3][n];
        ushort4 h, l;
        h.x = f2bf_rne(a0); l.x = f2bf_rne(a0 - bf2f(h.x));
        h.y = f2bf_rne(a1); l.y = f2bf_rne(a1 - bf2f(h.y));
        h.z = f2bf_rne(a2); l.z = f2bf_rne(a2 - bf2f(h.z));
        h.w = f2bf_rne(a3); l.w = f2bf_rne(a3 - bf2f(h.w));
        size_t o = (size_t)(nb + n) * K + kb + k4;
        *(ushort4*)&th[o] = h;
        *(ushort4*)&tl[o] = l;
    }
}

// ---------------------------------------------------------------------------
// MFMA GEMM body, split-bf16 operands. Double-buffered LDS (T3 minimum
// 2-phase): stage tile k+1 into buf^1 BEFORE compute of buf, one
// __syncthreads per K-step (its vmcnt drain lands ~compute-time after issue).
// LDS XOR swizzle (validated r6, conflicts=0): linear dest, pre-swizzled
// global source slot, swizzled read slot.
// OMODE: 0 = fp32 out, 1 = split planes out, 2 = hi-only bf16 out.
// ---------------------------------------------------------------------------
template<bool RELU, int OMODE>
__device__ __forceinline__ void gemm_body(
        const ushort* __restrict__ Ah, const ushort* __restrict__ Al,
        const ushort* __restrict__ Bh, const ushort* __restrict__ Bl,
        const float* __restrict__ bias,
        float* __restrict__ C, ushort* __restrict__ Ch, ushort* __restrict__ Cl,
        int M, int N, int Kd, int brow, int bcol)
{
    __shared__ __align__(16) ushort sAll[2][4][128 * 32];   // 64KB dbuf

    const int t    = threadIdx.x;
    const int lane = t & 63;
    const int w    = t >> 6;
    const int wr   = (w >> 1) * 64;
    const int wc   = (w & 1) * 64;

    f32x4_t acc[4][4];
    #pragma unroll
    for (int i = 0; i < 4; ++i)
        #pragma unroll
        for (int j = 0; j < 4; ++j)
            acc[i][j] = (f32x4_t){0.f, 0.f, 0.f, 0.f};

    const int fr = lane & 15;
    const int g  = lane >> 4;
    const int sS = ((g ^ ((fr >> 1) & 3)) << 3);   // swizzled k-slot (ushorts)

    // staging: wave w owns plane w; lane covers row (lane>>2), swizzled slot
    const ushort* gplane = (w == 0) ? Ah : (w == 1) ? Al : (w == 2) ? Bh : Bl;
    const int     rb     = (w < 2) ? brow : bcol;
    const size_t  grow   = (size_t)(rb + (lane >> 2)) * Kd
                         + (((lane & 3) ^ ((lane >> 3) & 3)) << 3);

    // prologue: stage k0=0 into buf 0
    {
        ushort* lp = &sAll[0][w][0];
        #pragma unroll
        for (int i = 0; i < 8; ++i)
            gl_lds16(gplane + grow + (size_t)(16 * i) * Kd, lp + i * 512);
    }
    __syncthreads();   // drains vmcnt -> buf0 visible

    int cur = 0;
    for (int k0 = 0; k0 < Kd; k0 += 32) {
        if (k0 + 32 < Kd) {          // prefetch next tile into buf^1
            ushort* lp = &sAll[cur ^ 1][w][0];
            #pragma unroll
            for (int i = 0; i < 8; ++i)
                gl_lds16(gplane + grow + (size_t)(16 * i) * Kd + k0 + 32, lp + i * 512);
        }
        __builtin_amdgcn_sched_barrier(0);   // pin prefetch issue before reads

        bf16x8_t ah[4], al[4], bh[4], bl[4];
        #pragma unroll
        for (int i = 0; i < 4; ++i) {
            int m = wr + i * 16 + fr;
            ah[i] = *(const bf16x8_t*)&sAll[cur][0][m * 32 + sS];
            al[i] = *(const bf16x8_t*)&sAll[cur][1][m * 32 + sS];
        }
        #pragma unroll
        for (int j = 0; j < 4; ++j) {
            int n = wc + j * 16 + fr;
            bh[j] = *(const bf16x8_t*)&sAll[cur][2][n * 32 + sS];
            bl[j] = *(const bf16x8_t*)&sAll[cur][3][n * 32 + sS];
        }
        #pragma unroll
        for (int i = 0; i < 4; ++i)
            #pragma unroll
            for (int j = 0; j < 4; ++j) {
                acc[i][j] = __builtin_amdgcn_mfma_f32_16x16x32_bf16(ah[i], bh[j], acc[i][j], 0, 0, 0);
                acc[i][j] = __builtin_amdgcn_mfma_f32_16x16x32_bf16(ah[i], bl[j], acc[i][j], 0, 0, 0);
                acc[i][j] = __builtin_amdgcn_mfma_f32_16x16x32_bf16(al[i], bh[j], acc[i][j], 0, 0, 0);
            }

        __syncthreads();   // readers done + prefetch drained
        cur ^= 1;
    }

    const int cl = lane & 15;
    const int rq = (lane >> 4) * 4;
    #pragma unroll
    for (int j = 0; j < 4; ++j) {
        int col = bcol + wc + j * 16 + cl;
        float bv = bias[col];
        #pragma unroll
        for (int i = 0; i < 4; ++i) {
            #pragma unroll
            for (int r = 0; r < 4; ++r) {
                int row = brow + wr + i * 16 + rq + r;
                float v = acc[i][j][r] + bv;
                if (RELU) v = fmaxf(v, 0.f);
                if (OMODE == 1) {
                    ushort h = f2bf_rne(v);
                    Ch[(size_t)row * N + col] = h;
                    Cl[(size_t)row * N + col] = f2bf_rne(v - bf2f(h));
                } else if (OMODE == 2) {
                    Ch[(size_t)row * N + col] = f2bf_rne(v);
                } else {
                    C[(size_t)row * N + col] = v;
                }
            }
        }
    }
}

// bijective XCD-chunked swizzle (nwg % 8 == 0 for all our grids)
__device__ __forceinline__ void swz_block(int& brow, int& bcol) {
    const int nx  = gridDim.x;
    const int lin = blockIdx.y * nx + blockIdx.x;
    const int cpx = (nx * gridDim.y) >> 3;
    const int swz = (lin & 7) * cpx + (lin >> 3);
    brow = (swz / nx) * 128;
    bcol = (swz % nx) * 128;
}

template<bool RELU, int OMODE>
__global__ __launch_bounds__(256) void gemm_mfma(
        const ushort* __restrict__ Ah, const ushort* __restrict__ Al,
        const ushort* __restrict__ Bh, const ushort* __restrict__ Bl,
        const float* __restrict__ bias,
        float* __restrict__ C, ushort* __restrict__ Ch, ushort* __restrict__ Cl,
        int M, int N, int Kd)
{
    int brow, bcol;
    swz_block(brow, bcol);
    gemm_body<RELU, OMODE>(Ah, Al, Bh, Bl, bias, C, Ch, Cl, M, N, Kd, brow, bcol);
}

// q/k/v projections fused into one dispatch (grid.z = 3 -> 768 blocks)
struct QkvArgs {
    const ushort* Ah[3]; const ushort* Al[3];
    const ushort* Bh[3]; const ushort* Bl[3];
    const float*  bias[3];
    ushort*       Co[3];
};

__global__ __launch_bounds__(256) void gemm_qkv(QkvArgs qa, int M, int N, int Kd)
{
    int brow, bcol;
    swz_block(brow, bcol);
    const int z = blockIdx.z;
    gemm_body<false, 2>(qa.Ah[z], qa.Al[z], qa.Bh[z], qa.Bl[z], qa.bias[z],
                        nullptr, qa.Co[z], nullptr, M, N, Kd, brow, bcol);
}

// ---------------------------------------------------------------------------
// MFMA flash attention (validated round 4). 1024 blocks, 4 waves, QBLK=64,
// KVBLK=32; online softmax via 16-lane shfl_xor; output split planes.
// ---------------------------------------------------------------------------
__global__ __launch_bounds__(256) void flash_attn_mfma(
        const ushort* __restrict__ qh, const ushort* __restrict__ kh,
        const ushort* __restrict__ vh,
        ushort* __restrict__ Oh, ushort* __restrict__ Ol)
{
    __shared__ __align__(16) ushort sk[32 * 72];
    __shared__ __align__(16) ushort svt[64 * 40];
    __shared__ __align__(16) ushort pbuf[4][16 * 40];

    const int bid  = blockIdx.x;
    const int slot = bid >> 3;
    const int bh   = (bid & 7) * 8 + (slot >> 4);
    const int qt   = slot & 15;
    const int b    = bh >> 4;
    const int h    = bh & 15;
    const int qb   = qt * 64;

    const int t = threadIdx.x, lane = t & 63, w = t >> 6;
    const int l15 = lane & 15, g = lane >> 4;

    bf16x8_t qf[2];
    {
        size_t qrow = ((size_t)(b * NQ_) + qb + w * 16 + l15) * D_ + h * DH_;
        qf[0] = *(const bf16x8_t*)&qh[qrow + 0  + 8 * g];
        qf[1] = *(const bf16x8_t*)&qh[qrow + 32 + 8 * g];
    }

    f32x4_t acc[4];
    #pragma unroll
    for (int dt = 0; dt < 4; ++dt) acc[dt] = (f32x4_t){0.f, 0.f, 0.f, 0.f};
    float m[4]    = {-INFINITY, -INFINITY, -INFINITY, -INFINITY};
    float lsum[4] = {0.f, 0.f, 0.f, 0.f};

    const int kkv = t >> 3,  kds = (t & 7) * 8;
    const int vkv = t & 31,  vds = (t >> 5) * 8;
    const size_t kvbase = (size_t)(b * NK_) * D_ + h * DH_;

    for (int kt = 0; kt < NK_; kt += 32) {
        __syncthreads();
        {
            bf16x8_t kk = *(const bf16x8_t*)&kh[kvbase + (size_t)(kt + kkv) * D_ + kds];
            *(bf16x8_t*)&sk[kkv * 72 + kds] = kk;
            bf16x8_t vv = *(const bf16x8_t*)&vh[kvbase + (size_t)(kt + vkv) * D_ + vds];
            #pragma unroll
            for (int j = 0; j < 8; ++j)
                svt[(vds + j) * 40 + vkv] = (ushort)vv[j];
        }
        __syncthreads();

        f32x4_t s0 = (f32x4_t){0.f,0.f,0.f,0.f};
        f32x4_t s1 = (f32x4_t){0.f,0.f,0.f,0.f};
        #pragma unroll
        for (int c = 0; c < 2; ++c) {
            bf16x8_t k0 = *(const bf16x8_t*)&sk[(l15     ) * 72 + 32 * c + 8 * g];
            bf16x8_t k1 = *(const bf16x8_t*)&sk[(l15 + 16) * 72 + 32 * c + 8 * g];
            s0 = __builtin_amdgcn_mfma_f32_16x16x32_bf16(qf[c], k0, s0, 0, 0, 0);
            s1 = __builtin_amdgcn_mfma_f32_16x16x32_bf16(qf[c], k1, s1, 0, 0, 0);
        }

        float p0[4], p1[4], corr[4];
        #pragma unroll
        for (int r = 0; r < 4; ++r) {
            float e0 = s0[r] * SCALE_, e1 = s1[r] * SCALE_;
            float tm = fmaxf(e0, e1);
            tm = fmaxf(tm, __shfl_xor(tm, 1, 64));
            tm = fmaxf(tm, __shfl_xor(tm, 2, 64));
            tm = fmaxf(tm, __shfl_xor(tm, 4, 64));
            tm = fmaxf(tm, __shfl_xor(tm, 8, 64));
            float mn = fmaxf(m[r], tm);
            corr[r] = __expf(m[r] - mn);
            p0[r] = __expf(e0 - mn);
            p1[r] = __expf(e1 - mn);
            float ps = p0[r] + p1[r];
            ps += __shfl_xor(ps, 1, 64);
            ps += __shfl_xor(ps, 2, 64);
            ps += __shfl_xor(ps, 4, 64);
            ps += __shfl_xor(ps, 8, 64);
            lsum[r] = lsum[r] * corr[r] + ps;
            m[r] = mn;
        }
        #pragma unroll
        for (int dt = 0; dt < 4; ++dt)
            #pragma unroll
            for (int r = 0; r < 4; ++r)
                acc[dt][r] *= corr[r];

        ushort* pw = &pbuf[w][0];
        #pragma unroll
        for (int r = 0; r < 4; ++r) {
            pw[(4 * g + r) * 40 + l15     ] = f2bf_rne(p0[r]);
            pw[(4 * g + r) * 40 + l15 + 16] = f2bf_rne(p1[r]);
        }
        bf16x8_t pa = *(const bf16x8_t*)&pw[l15 * 40 + 8 * g];

        #pragma unroll
        for (int dt = 0; dt < 4; ++dt) {
            bf16x8_t vf = *(const bf16x8_t*)&svt[(16 * dt + l15) * 40 + 8 * g];
            acc[dt] = __builtin_amdgcn_mfma_f32_16x16x32_bf16(pa, vf, acc[dt], 0, 0, 0);
        }
    }

    float inv[4];
    #pragma unroll
    for (int r = 0; r < 4; ++r) inv[r] = 1.0f / lsum[r];
    #pragma unroll
    for (int dt = 0; dt < 4; ++dt) {
        #pragma unroll
        for (int r = 0; r < 4; ++r) {
            int row = b * NQ_ + qb + w * 16 + 4 * g + r;
            int col = h * DH_ + 16 * dt + l15;
            float v = acc[dt][r] * inv[r];
            ushort hh = f2bf_rne(v);
            Oh[(size_t)row * D_ + col] = hh;
            Ol[(size_t)row * D_ + col] = f2bf_rne(v - bf2f(hh));
        }
    }
}

// ---------------------------------------------------------------------------
// out = LayerNorm(a + r) * g + be. SPLIT: also emit bf16 hi/lo planes.
// ---------------------------------------------------------------------------
template<bool SPLIT>
__global__ __launch_bounds__(256) void add_ln(const float* __restrict__ a,
        const float* __restrict__ r, const float* __restrict__ g,
        const float* __restrict__ be, float* __restrict__ out,
        ushort* __restrict__ oh, ushort* __restrict__ ol)
{
    const int row = blockIdx.x;
    const int t = threadIdx.x;
    float vals[4];
    float s1 = 0.0f, s2 = 0.0f;
    #pragma unroll
    for (int i = 0; i < 4; ++i) {
        int col = t + i * 256;
        float vv = a[(size_t)row * D_ + col] + r[(size_t)row * D_ + col];
        vals[i] = vv;
        s1 += vv;
        s2 += vv * vv;
    }
    #pragma unroll
    for (int off = 32; off > 0; off >>= 1) {
        s1 += __shfl_down(s1, off, 64);
        s2 += __shfl_down(s2, off, 64);
    }
    __shared__ float p1[4], p2[4];
    const int wave = t >> 6;
    if ((t & 63) == 0) { p1[wave] = s1; p2[wave] = s2; }
    __syncthreads();
    s1 = p1[0] + p1[1] + p1[2] + p1[3];
    s2 = p2[0] + p2[1] + p2[2] + p2[3];
    const float mean = s1 * (1.0f / D_);
    const float var  = s2 * (1.0f / D_) - mean * mean;
    const float rstd = rsqrtf(var + LN_EPS_);
    #pragma unroll
    for (int i = 0; i < 4; ++i) {
        int col = t + i * 256;
        float v = (vals[i] - mean) * rstd * g[col] + be[col];
        out[(size_t)row * D_ + col] = v;
        if (SPLIT) {
            ushort h = f2bf_rne(v);
            oh[(size_t)row * D_ + col] = h;
            ol[(size_t)row * D_ + col] = f2bf_rne(v - bf2f(h));
        }
    }
}

// ---------------------------------------------------------------------------
extern "C" void kernel_launch(void* const* d_in, const int* in_sizes, int n_in,
                              void* d_out, int out_size, void* d_ws, size_t ws_size,
                              hipStream_t stream)
{
    const float* Q   = (const float*)d_in[0];
    const float* K   = (const float*)d_in[1];
    const float* Wq  = (const float*)d_in[2];
    const float* bq  = (const float*)d_in[3];
    const float* Wk  = (const float*)d_in[4];
    const float* bk  = (const float*)d_in[5];
    const float* Wv  = (const float*)d_in[6];
    const float* bv  = (const float*)d_in[7];
    const float* Wo  = (const float*)d_in[8];
    const float* bo  = (const float*)d_in[9];
    const float* W1  = (const float*)d_in[10];
    const float* b1  = (const float*)d_in[11];
    const float* W2  = (const float*)d_in[12];
    const float* b2  = (const float*)d_in[13];
    const float* g0  = (const float*)d_in[14];
    const float* be0 = (const float*)d_in[15];
    const float* g1  = (const float*)d_in[16];
    const float* be1 = (const float*)d_in[17];

    unsigned char* Wb = (unsigned char*)d_ws;
    const size_t MBy = 1ull << 20;

    ushort* Qh  = (ushort*)(Wb +  0 * MBy);
    ushort* Ql  = (ushort*)(Wb +  8 * MBy);
    ushort* Kh  = (ushort*)(Wb + 16 * MBy);
    ushort* Kl  = (ushort*)(Wb + 24 * MBy);
    ushort* Wqh = (ushort*)(Wb + 32 * MBy);
    ushort* Wql = (ushort*)(Wb + 34 * MBy);
    ushort* Wkh = (ushort*)(Wb + 36 * MBy);
    ushort* Wkl = (ushort*)(Wb + 38 * MBy);
    ushort* Wvh = (ushort*)(Wb + 40 * MBy);
    ushort* Wvl = (ushort*)(Wb + 42 * MBy);
    ushort* Woh = (ushort*)(Wb + 44 * MBy);
    ushort* Wol = (ushort*)(Wb + 46 * MBy);
    ushort* qhp = (ushort*)(Wb + 48 * MBy);
    ushort* khp = (ushort*)(Wb + 56 * MBy);
    ushort* vhp = (ushort*)(Wb + 64 * MBy);
    ushort* aOh = (ushort*)(Wb + 72 * MBy);
    ushort* aOl = (ushort*)(Wb + 80 * MBy);

    float*  oprj = (float*)(Wb + 16 * MBy);
    float*  Xf   = (float*)(Wb +  0 * MBy);
    ushort* Xh   = (ushort*)(Wb + 48 * MBy);
    ushort* Xl   = (ushort*)(Wb + 56 * MBy);
    ushort* W1h  = (ushort*)(Wb + 64 * MBy);
    ushort* W1l  = (ushort*)(Wb + 72 * MBy);
    ushort* Hih  = (ushort*)(Wb + 80 * MBy);   // 32MB
    ushort* Hil  = (ushort*)(Wb + 16 * MBy);   // 32MB
    ushort* W2h  = (ushort*)(Wb + 48 * MBy);
    ushort* W2l  = (ushort*)(Wb + 56 * MBy);
    float*  Y    = (float*)(Wb + 64 * MBy);

    const int M = B_ * NQ_;
    const int n4act = M * D_ / 4;
    dim3 blk(256);
    dim3 gD(D_ / 128, M / 128);
    dim3 gQKV(D_ / 128, M / 128, 3);
    dim3 gF(DFF_ / 128, M / 128);

    split_rows<<<n4act / 256, blk, 0, stream>>>(Q, Qh, Ql, n4act);
    split_rows<<<n4act / 256, blk, 0, stream>>>(K, Kh, Kl, n4act);
    split_tr<<<dim3(D_/32, D_/32), blk, 0, stream>>>(Wq, Wqh, Wql, D_, D_);
    split_tr<<<dim3(D_/32, D_/32), blk, 0, stream>>>(Wk, Wkh, Wkl, D_, D_);
    split_tr<<<dim3(D_/32, D_/32), blk, 0, stream>>>(Wv, Wvh, Wvl, D_, D_);
    split_tr<<<dim3(D_/32, D_/32), blk, 0, stream>>>(Wo, Woh, Wol, D_, D_);

    QkvArgs qa;
    qa.Ah[0] = Qh;  qa.Al[0] = Ql;  qa.Bh[0] = Wqh; qa.Bl[0] = Wql; qa.bias[0] = bq; qa.Co[0] = qhp;
    qa.Ah[1] = Kh;  qa.Al[1] = Kl;  qa.Bh[1] = Wkh; qa.Bl[1] = Wkl; qa.bias[1] = bk; qa.Co[1] = khp;
    qa.Ah[2] = Kh;  qa.Al[2] = Kl;  qa.Bh[2] = Wvh; qa.Bl[2] = Wvl; qa.bias[2] = bv; qa.Co[2] = vhp;
    gemm_qkv<<<gQKV, blk, 0, stream>>>(qa, M, D_, D_);

    flash_attn_mfma<<<dim3(1024), blk, 0, stream>>>(qhp, khp, vhp, aOh, aOl);

    gemm_mfma<false,0><<<gD, blk, 0, stream>>>(aOh, aOl, Woh, Wol, bo, oprj, nullptr, nullptr, M, D_, D_);
    add_ln<true><<<M, blk, 0, stream>>>(oprj, Q, g0, be0, Xf, Xh, Xl);

    split_tr<<<dim3(DFF_/32, D_/32), blk, 0, stream>>>(W1, W1h, W1l, D_, DFF_);
    gemm_mfma<true,1><<<gF, blk, 0, stream>>>(Xh, Xl, W1h, W1l, b1, nullptr, Hih, Hil, M, DFF_, D_);
    split_tr<<<dim3(D_/32, DFF_/32), blk, 0, stream>>>(W2, W2h, W2l, DFF_, D_);
    gemm_mfma<false,0><<<gD, blk, 0, stream>>>(Hih, Hil, W2h, W2l, b2, Y, nullptr, nullptr, M, D_, DFF_);
    add_ln<false><<<M, blk, 0, stream>>>(Y, Xf, g1, be1, (float*)d_out, nullptr, nullptr);
}